// Round 3
// baseline (350.970 us; speedup 1.0000x reference)
//
#include <hip/hip_runtime.h>
#include <math.h>

// Single-query MHA, algebraically collapsed:
//   s[l,h] = x_l . p_h         (p_h = Wk_h^T q_h / sqrt(D); k-bias shift cancels in softmax)
//   z_h    = sum_l softmax(s)_lh * x_l
//   attn   = Wv z + bv ; out = Wo attn + bo
// All fp32. No max-subtraction: |s| ~ N(0,1), far from fp32 exp range.
//
// v7 (mha_all): ENTIRE pipeline in ONE dispatch (+ one 64B memset). Evidence:
// v5->v6 changed kernel work substantially, dur_us moved 0.5% -> measured time
// is dominated by fixed per-iteration overhead (512MiB poison fills ~78us each
// in profile) + 6 dispatch gaps. Only the gaps are ours to remove.
// Stages separated by a device-scope sense-reversal grid barrier in workspace.
// Co-residency by construction: 256 blocks (=1 grid's worth at >=1 blk/CU;
// LDS 64.4KB + VGPR<=128 under __launch_bounds__(512,2) give capacity >=2/CU),
// so the software barrier cannot deadlock. All ops are graph-capturable.
// attn core = v6's verified attn_fused5 body (math unchanged), rows_per_blk=128.

#define L_SEQ   32768
#define E_DIM   1024
#define NHEAD   8
#define HDIM    128
#define TILE_R  8
#define NBLK    256          // fused-kernel grid; 128 rows per block

// direct HBM->LDS, 16B per lane; gptr is PER-LANE, ldsptr is wave-uniform base
#define GLD16(gp, lp)                                                   \
  __builtin_amdgcn_global_load_lds(                                     \
      (const __attribute__((address_space(1))) void*)(gp),              \
      (__attribute__((address_space(3))) void*)(lp), 16, 0, 0)

// device-scope grid barrier: bar[0]=arrive counter, bar[1]=released phase.
// Safe because all NBLK blocks are co-resident (see header comment).
__device__ __forceinline__ void grid_barrier(int* bar, int phase)
{
  __syncthreads();
  if (threadIdx.x == 0) {
    if (__hip_atomic_fetch_add(&bar[0], 1, __ATOMIC_ACQ_REL,
                               __HIP_MEMORY_SCOPE_AGENT) == NBLK - 1) {
      __hip_atomic_store(&bar[0], 0, __ATOMIC_RELAXED, __HIP_MEMORY_SCOPE_AGENT);
      __hip_atomic_store(&bar[1], phase, __ATOMIC_RELEASE, __HIP_MEMORY_SCOPE_AGENT);
    } else {
      while (__hip_atomic_load(&bar[1], __ATOMIC_ACQUIRE,
                               __HIP_MEMORY_SCOPE_AGENT) < phase) {}
    }
  }
  __syncthreads();
}

__global__ __launch_bounds__(512, 2) void mha_all(
    const float* __restrict__ x,   const float* __restrict__ Wi,
    const float* __restrict__ bi,  const float* __restrict__ Wo,
    const float* __restrict__ bo,  float* __restrict__ out,
    float* __restrict__ q,   float* __restrict__ P_T,
    float* __restrict__ zn,  float* __restrict__ attn,
    float* __restrict__ psumw, float* __restrict__ pz,
    int* bar)
{
  __shared__ __align__(16) float sbuf[2][TILE_R][E_DIM];   // 64 KB, reused per stage
  __shared__ float swst[16];
  __shared__ __align__(16) float swst4[8][NHEAD];
  __shared__ float sumw_s[NHEAD];

  const int t    = threadIdx.x;
  const int wave = t >> 6;
  const int lane = t & 63;
  const int bid  = blockIdx.x;

  // ---------------- S1: q = Wq x0 + bq (blocks 0..127, wave-per-output) ----------------
  if (bid < 128) {
    const int o = bid * 8 + wave;
    const float4* Wr = (const float4*)(Wi + (size_t)o * E_DIM);
    const float4* xr = (const float4*)x;           // row 0 of x
    float a = 0.f;
#pragma unroll
    for (int k = 0; k < 4; ++k) {
      float4 wv = Wr[lane + 64 * k];
      float4 xv = xr[lane + 64 * k];
      a += wv.x * xv.x + wv.y * xv.y + wv.z * xv.z + wv.w * xv.w;
    }
#pragma unroll
    for (int m = 1; m < 64; m <<= 1) a += __shfl_xor(a, m, 64);
    if (lane == 0) q[o] = a + bi[o];
  }
  grid_barrier(bar, 1);

  // ---------------- S2: P_T[h][e] = (1/sqrt(D)) Wk_h^T q_h (blocks 0..127) ----------------
  if (bid < 128) {
    float4 (*ps)[16] = (float4(*)[16])&sbuf[0][0][0];   // [32][16] float4 = 8 KB
    const int h   = bid >> 4;           // head
    const int ec2 = bid & 15;           // 64-wide e-chunk
    const int eg  = t & 15;             // float4 slot within chunk
    const int dg  = t >> 4;             // d-group of 4 (32 groups)
    const float* Wb = Wi + ((size_t)E_DIM + h * HDIM + dg * 4) * E_DIM + ec2 * 64 + eg * 4;
    const float* qh = q + h * HDIM + dg * 4;
    float4 a = make_float4(0.f, 0.f, 0.f, 0.f);
#pragma unroll
    for (int dd = 0; dd < 4; ++dd) {
      const float qv = qh[dd];
      const float4 wv = *(const float4*)(Wb + (size_t)dd * E_DIM);
      a.x += qv * wv.x; a.y += qv * wv.y; a.z += qv * wv.z; a.w += qv * wv.w;
    }
    ps[dg][eg] = a;
    __syncthreads();
    if (t < 16) {
      float4 s = ps[0][t];
#pragma unroll
      for (int g = 1; g < 32; ++g) {
        const float4 b = ps[g][t];
        s.x += b.x; s.y += b.y; s.z += b.z; s.w += b.w;
      }
      const float sc = 0.08838834764831845f;   // 1/sqrt(128)
      s.x *= sc; s.y *= sc; s.z *= sc; s.w *= sc;
      *(float4*)(P_T + (size_t)h * E_DIM + ec2 * 64 + t * 4) = s;
    }
  }
  grid_barrier(bar, 2);

  // ---------------- S3: fused scores + softmax-weights + weighted-x (all blocks) ----------------
  {
    const int rh = wave >> 2;          // row half
    const int h0 = (wave & 3) * 2;     // head pair base
    const size_t row0 = (size_t)bid * (L_SEQ / NBLK);
    const int ntiles  = (L_SEQ / NBLK) / TILE_R;    // 16

    float4 p0[4], p1[4];
    {
      const float4* P0 = (const float4*)(P_T + (size_t)h0 * E_DIM);
      const float4* P1 = (const float4*)(P_T + (size_t)(h0 + 1) * E_DIM);
#pragma unroll
      for (int k = 0; k < 4; ++k) { p0[k] = P0[64 * k + lane]; p1[k] = P1[64 * k + lane]; }
    }

    float4 z0[4], z1[4];
#pragma unroll
    for (int k = 0; k < 4; ++k) {
      z0[k] = make_float4(0.f, 0.f, 0.f, 0.f);
      z1[k] = make_float4(0.f, 0.f, 0.f, 0.f);
    }
    float sumw0 = 0.f, sumw1 = 0.f;

    // prologue: stage tile 0 (wave stages row 'wave')
    {
      const float* g = x + (row0 + wave) * E_DIM + 4 * lane;
#pragma unroll
      for (int k = 0; k < 4; ++k) GLD16(g + k * 256, &sbuf[0][wave][k * 256]);
    }
    __syncthreads();

    for (int tile = 0; tile < ntiles; ++tile) {
      const int buf = tile & 1;

      if (tile + 1 < ntiles) {
        const float* g = x + (row0 + (size_t)(tile + 1) * TILE_R + wave) * E_DIM + 4 * lane;
#pragma unroll
        for (int k = 0; k < 4; ++k) GLD16(g + k * 256, &sbuf[buf ^ 1][wave][k * 256]);
      }

#pragma unroll
      for (int rl = 0; rl < 4; ++rl) {
        const float4* xr4 = (const float4*)&sbuf[buf][rh * 4 + rl][0];
        float4 xr[4];
#pragma unroll
        for (int k = 0; k < 4; ++k) xr[k] = xr4[64 * k + lane];

        float s0 = 0.f, s1 = 0.f;
#pragma unroll
        for (int k = 0; k < 4; ++k) {
          s0 += xr[k].x * p0[k].x + xr[k].y * p0[k].y + xr[k].z * p0[k].z + xr[k].w * p0[k].w;
          s1 += xr[k].x * p1[k].x + xr[k].y * p1[k].y + xr[k].z * p1[k].z + xr[k].w * p1[k].w;
        }

        const bool odd = (lane & 1);
        float keep = odd ? s1 : s0;
        float oth  = odd ? s0 : s1;
        float ts = keep + __shfl_xor(oth, 1, 64);
        ts += __shfl_xor(ts, 2, 64);
        ts += __shfl_xor(ts, 4, 64);
        ts += __shfl_xor(ts, 8, 64);
        ts += __shfl_xor(ts, 16, 64);
        ts += __shfl_xor(ts, 32, 64);
        const float ex = __expf(ts);
        const float ox = __shfl_xor(ex, 1, 64);
        const float w0 = odd ? ox : ex;
        const float w1 = odd ? ex : ox;
        sumw0 += w0; sumw1 += w1;

#pragma unroll
        for (int k = 0; k < 4; ++k) {
          z0[k].x += w0 * xr[k].x; z0[k].y += w0 * xr[k].y;
          z0[k].z += w0 * xr[k].z; z0[k].w += w0 * xr[k].w;
          z1[k].x += w1 * xr[k].x; z1[k].y += w1 * xr[k].y;
          z1[k].z += w1 * xr[k].z; z1[k].w += w1 * xr[k].w;
        }
      }

      __syncthreads();
    }

    // intra-block combine of the two row-half partials via LDS reuse
    float (*zs)[E_DIM] = (float(*)[E_DIM])&sbuf[0][0][0];
    {
      float4* zd0 = (float4*)&zs[2 * wave][0];
      float4* zd1 = (float4*)&zs[2 * wave + 1][0];
#pragma unroll
      for (int k = 0; k < 4; ++k) { zd0[64 * k + lane] = z0[k]; zd1[64 * k + lane] = z1[k]; }
    }
    if (lane == 0) { swst[2 * wave] = sumw0; swst[2 * wave + 1] = sumw1; }
    __syncthreads();

    {
      const float4* zsv = (const float4*)&zs[0][0];
      float4* pzb = (float4*)(pz + (size_t)bid * (NHEAD * E_DIM));
#pragma unroll
      for (int j = 0; j < 4; ++j) {
        const int idx = t + 512 * j;                 // 0..2047 = h*256+e4
        const float4 a = zsv[idx], b = zsv[idx + 2048];
        pzb[idx] = make_float4(a.x + b.x, a.y + b.y, a.z + b.z, a.w + b.w);
      }
    }
    if (t < NHEAD)
      psumw[bid * NHEAD + t] = swst[t] + swst[t + 8];
  }
  grid_barrier(bar, 3);

  // ---------------- S4: zn[h][e] = sum_b pz / sum_b psumw (all 256 blocks) ----------------
  {
    float* red = &sbuf[0][0][0];                     // 512 floats
    float sw[NHEAD];
#pragma unroll
    for (int h = 0; h < NHEAD; ++h) sw[h] = 0.f;
    for (int b2 = t; b2 < NBLK; b2 += 512) {
      const float4* p = (const float4*)(psumw + (size_t)b2 * NHEAD);
      float4 a0 = p[0], a1 = p[1];
      sw[0] += a0.x; sw[1] += a0.y; sw[2] += a0.z; sw[3] += a0.w;
      sw[4] += a1.x; sw[5] += a1.y; sw[6] += a1.z; sw[7] += a1.w;
    }
#pragma unroll
    for (int m = 1; m < 64; m <<= 1) {
#pragma unroll
      for (int h = 0; h < NHEAD; ++h) sw[h] += __shfl_xor(sw[h], m, 64);
    }
    if (lane == 0) {
#pragma unroll
      for (int h = 0; h < NHEAD; ++h) swst4[wave][h] = sw[h];
    }
    __syncthreads();
    if (t < NHEAD) {
      float s = 0.f;
#pragma unroll
      for (int wv = 0; wv < 8; ++wv) s += swst4[wv][t];
      sumw_s[t] = s;
    }

    const int o = bid * 32 + (t & 31);
    const int g = t >> 5;                            // 16 column-groups
    float a = 0.f;
    for (int b2 = g; b2 < NBLK; b2 += 16) a += pz[(size_t)b2 * (NHEAD * E_DIM) + o];
    red[t] = a;
    __syncthreads();
    if (t < 32) {
      float s2 = 0.f;
#pragma unroll
      for (int gg = 0; gg < 16; ++gg) s2 += red[gg * 32 + t];
      const int oo = bid * 32 + t;
      zn[oo] = s2 / sumw_s[oo >> 10];                // oo = h*1024 + e
    }
  }
  grid_barrier(bar, 4);

  // ---------------- S5: attn[o] = Wv[o] . zn[h(o)] + bv[o] (blocks 0..127) ----------------
  if (bid < 128) {
    const int o = bid * 8 + wave;
    const float4* Wr = (const float4*)(Wi + ((size_t)2 * E_DIM + o) * E_DIM);
    const float4* zr = (const float4*)(zn + (size_t)(o >> 7) * E_DIM);
    float a = 0.f;
#pragma unroll
    for (int k = 0; k < 4; ++k) {
      float4 wv = Wr[lane + 64 * k];
      float4 zv = zr[lane + 64 * k];
      a += wv.x * zv.x + wv.y * zv.y + wv.z * zv.z + wv.w * zv.w;
    }
#pragma unroll
    for (int m = 1; m < 64; m <<= 1) a += __shfl_xor(a, m, 64);
    if (lane == 0) attn[o] = a + bi[2 * E_DIM + o];
  }
  grid_barrier(bar, 5);

  // ---------------- S6: out[e] = Wo[e] . attn + bo[e] (blocks 0..127) ----------------
  if (bid < 128) {
    const int o = bid * 8 + wave;
    const float4* Wr = (const float4*)(Wo + (size_t)o * E_DIM);
    const float4* vr = (const float4*)attn;
    float a = 0.f;
#pragma unroll
    for (int k = 0; k < 4; ++k) {
      float4 wv = Wr[lane + 64 * k];
      float4 vv = vr[lane + 64 * k];
      a += wv.x * vv.x + wv.y * vv.y + wv.z * vv.z + wv.w * vv.w;
    }
#pragma unroll
    for (int m = 1; m < 64; m <<= 1) a += __shfl_xor(a, m, 64);
    if (lane == 0) out[o] = a + bo[o];
  }
}

// ================= fallback multi-kernel path (used only if ws too small) =================

__global__ __launch_bounds__(256) void proj_q(
    const float* __restrict__ W, const float* __restrict__ bias,
    const float* __restrict__ x, float* __restrict__ q)
{
  const int t = threadIdx.x, wave = t >> 6, lane = t & 63;
  const int o = blockIdx.x * 4 + wave;
  const float4* Wr = (const float4*)(W + (size_t)o * E_DIM);
  const float4* xr = (const float4*)x;
  float a = 0.f;
#pragma unroll
  for (int k = 0; k < 4; ++k) {
    float4 wv = Wr[lane + 64 * k];
    float4 xv = xr[lane + 64 * k];
    a += wv.x * xv.x + wv.y * xv.y + wv.z * xv.z + wv.w * xv.w;
  }
#pragma unroll
  for (int m = 1; m < 64; m <<= 1) a += __shfl_xor(a, m, 64);
  if (lane == 0) q[o] = a + bias[o];
}

__global__ __launch_bounds__(128) void make_p(
    const float* __restrict__ W, const float* __restrict__ q,
    float* __restrict__ P_T)
{
  const int h = blockIdx.y;
  const int e = blockIdx.x * 128 + threadIdx.x;
  const float* qh = q + h * HDIM;
  const float* Wb = W + ((size_t)E_DIM + (size_t)h * HDIM) * E_DIM + e;
  float a0 = 0.f, a1 = 0.f, a2 = 0.f, a3 = 0.f;
#pragma unroll 4
  for (int d = 0; d < HDIM; d += 4) {
    a0 += qh[d + 0] * Wb[(size_t)(d + 0) * E_DIM];
    a1 += qh[d + 1] * Wb[(size_t)(d + 1) * E_DIM];
    a2 += qh[d + 2] * Wb[(size_t)(d + 2) * E_DIM];
    a3 += qh[d + 3] * Wb[(size_t)(d + 3) * E_DIM];
  }
  P_T[h * E_DIM + e] = ((a0 + a1) + (a2 + a3)) * 0.08838834764831845f;
}

__global__ __launch_bounds__(512, 2) void attn_fused5(
    const float* __restrict__ x, const float* __restrict__ P_T,
    float* __restrict__ partial_z, float* __restrict__ partial_sumw,
    int rows_per_blk)
{
  __shared__ __align__(16) float sbuf[2][TILE_R][E_DIM];
  __shared__ float swst[16];
  const int t = threadIdx.x, wave = t >> 6, lane = t & 63;
  const int rh = wave >> 2, h0 = (wave & 3) * 2;
  const size_t row0 = (size_t)blockIdx.x * rows_per_blk;
  const int ntiles = rows_per_blk / TILE_R;

  float4 p0[4], p1[4];
  {
    const float4* P0 = (const float4*)(P_T + (size_t)h0 * E_DIM);
    const float4* P1 = (const float4*)(P_T + (size_t)(h0 + 1) * E_DIM);
#pragma unroll
    for (int k = 0; k < 4; ++k) { p0[k] = P0[64 * k + lane]; p1[k] = P1[64 * k + lane]; }
  }
  float4 z0[4], z1[4];
#pragma unroll
  for (int k = 0; k < 4; ++k) {
    z0[k] = make_float4(0.f, 0.f, 0.f, 0.f);
    z1[k] = make_float4(0.f, 0.f, 0.f, 0.f);
  }
  float sumw0 = 0.f, sumw1 = 0.f;
  {
    const float* g = x + (row0 + wave) * E_DIM + 4 * lane;
#pragma unroll
    for (int k = 0; k < 4; ++k) GLD16(g + k * 256, &sbuf[0][wave][k * 256]);
  }
  __syncthreads();
  for (int tile = 0; tile < ntiles; ++tile) {
    const int buf = tile & 1;
    if (tile + 1 < ntiles) {
      const float* g = x + (row0 + (size_t)(tile + 1) * TILE_R + wave) * E_DIM + 4 * lane;
#pragma unroll
      for (int k = 0; k < 4; ++k) GLD16(g + k * 256, &sbuf[buf ^ 1][wave][k * 256]);
    }
#pragma unroll
    for (int rl = 0; rl < 4; ++rl) {
      const float4* xr4 = (const float4*)&sbuf[buf][rh * 4 + rl][0];
      float4 xr[4];
#pragma unroll
      for (int k = 0; k < 4; ++k) xr[k] = xr4[64 * k + lane];
      float s0 = 0.f, s1 = 0.f;
#pragma unroll
      for (int k = 0; k < 4; ++k) {
        s0 += xr[k].x * p0[k].x + xr[k].y * p0[k].y + xr[k].z * p0[k].z + xr[k].w * p0[k].w;
        s1 += xr[k].x * p1[k].x + xr[k].y * p1[k].y + xr[k].z * p1[k].z + xr[k].w * p1[k].w;
      }
      const bool odd = (lane & 1);
      float keep = odd ? s1 : s0;
      float oth  = odd ? s0 : s1;
      float ts = keep + __shfl_xor(oth, 1, 64);
      ts += __shfl_xor(ts, 2, 64);
      ts += __shfl_xor(ts, 4, 64);
      ts += __shfl_xor(ts, 8, 64);
      ts += __shfl_xor(ts, 16, 64);
      ts += __shfl_xor(ts, 32, 64);
      const float ex = __expf(ts);
      const float ox = __shfl_xor(ex, 1, 64);
      const float w0 = odd ? ox : ex;
      const float w1 = odd ? ex : ox;
      sumw0 += w0; sumw1 += w1;
#pragma unroll
      for (int k = 0; k < 4; ++k) {
        z0[k].x += w0 * xr[k].x; z0[k].y += w0 * xr[k].y;
        z0[k].z += w0 * xr[k].z; z0[k].w += w0 * xr[k].w;
        z1[k].x += w1 * xr[k].x; z1[k].y += w1 * xr[k].y;
        z1[k].z += w1 * xr[k].z; z1[k].w += w1 * xr[k].w;
      }
    }
    __syncthreads();
  }
  float (*zs)[E_DIM] = (float(*)[E_DIM])&sbuf[0][0][0];
  {
    float4* zd0 = (float4*)&zs[2 * wave][0];
    float4* zd1 = (float4*)&zs[2 * wave + 1][0];
#pragma unroll
    for (int k = 0; k < 4; ++k) { zd0[64 * k + lane] = z0[k]; zd1[64 * k + lane] = z1[k]; }
  }
  if (lane == 0) { swst[2 * wave] = sumw0; swst[2 * wave + 1] = sumw1; }
  __syncthreads();
  {
    const float4* zsv = (const float4*)&zs[0][0];
    float4* pzb = (float4*)(partial_z + (size_t)blockIdx.x * (NHEAD * E_DIM));
#pragma unroll
    for (int j = 0; j < 4; ++j) {
      const int idx = t + 512 * j;
      const float4 a = zsv[idx], b = zsv[idx + 2048];
      pzb[idx] = make_float4(a.x + b.x, a.y + b.y, a.z + b.z, a.w + b.w);
    }
  }
  if (t < NHEAD)
    partial_sumw[blockIdx.x * NHEAD + t] = swst[t] + swst[t + 8];
}

__global__ __launch_bounds__(256) void reduce_z(
    const float* __restrict__ partial_z, const float* __restrict__ partial_sumw,
    float* __restrict__ zn, int nblk)
{
  __shared__ float red[256];
  __shared__ __align__(16) float swst[4][NHEAD];
  __shared__ float sumw_s[NHEAD];
  const int t = threadIdx.x;
  const int lane = t & 63, wave = t >> 6;
  float sw[NHEAD];
#pragma unroll
  for (int h = 0; h < NHEAD; ++h) sw[h] = 0.f;
  for (int b = t; b < nblk; b += 256) {
    const float4* p = (const float4*)(partial_sumw + (size_t)b * NHEAD);
    float4 a0 = p[0], a1 = p[1];
    sw[0] += a0.x; sw[1] += a0.y; sw[2] += a0.z; sw[3] += a0.w;
    sw[4] += a1.x; sw[5] += a1.y; sw[6] += a1.z; sw[7] += a1.w;
  }
#pragma unroll
  for (int m = 1; m < 64; m <<= 1) {
#pragma unroll
    for (int h = 0; h < NHEAD; ++h) sw[h] += __shfl_xor(sw[h], m, 64);
  }
  if (lane == 0) {
#pragma unroll
    for (int h = 0; h < NHEAD; ++h) swst[wave][h] = sw[h];
  }
  __syncthreads();
  if (t < NHEAD) sumw_s[t] = swst[0][t] + swst[1][t] + swst[2][t] + swst[3][t];
  const int o = blockIdx.x * 32 + (t & 31);
  const int g = t >> 5;
  float a = 0.f;
  for (int b = g; b < nblk; b += 8) a += partial_z[(size_t)b * (NHEAD * E_DIM) + o];
  red[t] = a;
  __syncthreads();
  if (t < 32) {
    float s2 = 0.f;
#pragma unroll
    for (int gg = 0; gg < 8; ++gg) s2 += red[gg * 32 + t];
    const int oo = blockIdx.x * 32 + t;
    zn[oo] = s2 / sumw_s[oo >> 10];
  }
}

__global__ __launch_bounds__(256) void proj_v(
    const float* __restrict__ W, const float* __restrict__ bias,
    const float* __restrict__ zn, float* __restrict__ attn)
{
  const int t = threadIdx.x, wave = t >> 6, lane = t & 63;
  const int o = blockIdx.x * 4 + wave;
  const float4* Wr = (const float4*)(W + ((size_t)2 * E_DIM + o) * E_DIM);
  const float4* zr = (const float4*)(zn + (size_t)(o >> 7) * E_DIM);
  float a = 0.f;
#pragma unroll
  for (int k = 0; k < 4; ++k) {
    float4 wv = Wr[lane + 64 * k];
    float4 zv = zr[lane + 64 * k];
    a += wv.x * zv.x + wv.y * zv.y + wv.z * zv.z + wv.w * zv.w;
  }
#pragma unroll
  for (int m = 1; m < 64; m <<= 1) a += __shfl_xor(a, m, 64);
  if (lane == 0) attn[o] = a + bias[2 * E_DIM + o];
}

__global__ __launch_bounds__(256) void proj_o(
    const float* __restrict__ Wo, const float* __restrict__ bo,
    const float* __restrict__ attn, float* __restrict__ out)
{
  const int t = threadIdx.x, wave = t >> 6, lane = t & 63;
  const int o = blockIdx.x * 4 + wave;
  const float4* Wr = (const float4*)(Wo + (size_t)o * E_DIM);
  const float4* vr = (const float4*)attn;
  float a = 0.f;
#pragma unroll
  for (int k = 0; k < 4; ++k) {
    float4 wv = Wr[lane + 64 * k];
    float4 vv = vr[lane + 64 * k];
    a += wv.x * vv.x + wv.y * vv.y + wv.z * vv.z + wv.w * vv.w;
  }
#pragma unroll
  for (int m = 1; m < 64; m <<= 1) a += __shfl_xor(a, m, 64);
  if (lane == 0) out[o] = a + bo[o];
}

extern "C" void kernel_launch(void* const* d_in, const int* in_sizes, int n_in,
                              void* d_out, int out_size, void* d_ws, size_t ws_size,
                              hipStream_t stream)
{
  const float* x  = (const float*)d_in[0];   // [32768,1024]
  const float* Wi = (const float*)d_in[1];   // [3072,1024]
  const float* bi = (const float*)d_in[2];   // [3072]
  const float* Wo = (const float*)d_in[3];   // [1024,1024]
  const float* bo = (const float*)d_in[4];   // [1024]
  float* out = (float*)d_out;                // [1024] fp32

  // workspace layout (bytes)
  char* ws = (char*)d_ws;
  float* q     = (float*)(ws + 0);           // 1024 f
  float* P_T   = (float*)(ws + 4096);        // 8192 f
  float* zn    = (float*)(ws + 36864);       // 8192 f
  float* attn  = (float*)(ws + 69632);       // 1024 f
  float* psumw = (float*)(ws + 73728);       // nblk*8 f
  int*   bar   = (int*)  (ws + 81920);       // 2 ints (grid barrier)
  const size_t pz_off = 90112;
  float* pz    = (float*)(ws + pz_off);      // nblk*8192 f

  const size_t need_coop = pz_off + (size_t)NBLK * NHEAD * E_DIM * 4;
  if (ws_size >= need_coop) {
    hipMemsetAsync(bar, 0, 64, stream);      // re-zero barrier (ws is re-poisoned per iter)
    mha_all<<<NBLK, 512, 0, stream>>>(x, Wi, bi, Wo, bo, out,
                                      q, P_T, zn, attn, psumw, pz, bar);
    return;
  }

  // fallback (small workspace): original 6-dispatch pipeline
  int nblk = 128;
  if (ws_size >= pz_off + (size_t)512 * NHEAD * E_DIM * 4) nblk = 512;
  else if (ws_size >= pz_off + (size_t)256 * NHEAD * E_DIM * 4) nblk = 256;
  const int rows_per_blk = L_SEQ / nblk;

  proj_q     <<<256, 256, 0, stream>>>(Wi, bi, x, q);
  make_p     <<<dim3(8, 8), 128, 0, stream>>>(Wi, q, P_T);
  attn_fused5<<<nblk, 512, 0, stream>>>(x, P_T, pz, psumw, rows_per_blk);
  reduce_z   <<<256, 256, 0, stream>>>(pz, psumw, zn, nblk);
  proj_v     <<<256, 256, 0, stream>>>(Wi, bi, zn, attn);
  proj_o     <<<256, 256, 0, stream>>>(Wo, bo, attn, out);
}

// Round 4
// 330.439 us; speedup vs baseline: 1.0621x; 1.0621x over previous
//
#include <hip/hip_runtime.h>
#include <math.h>

// Single-query MHA, algebraically collapsed:
//   s[l,h] = x_l . p_h   (p_h = Wk_h^T q_h / sqrt(D); k-bias shift cancels in softmax)
//   z_h    = sum_l softmax(s)_lh * x_l ;  attn = Wv z + bv ; out = Wo attn + bo
//
// v8: single-dispatch pipeline, both v7 bottlenecks fixed:
//  (a) grid barrier: hierarchical arrival counters on 8 separate cachelines
//      (bid&7) + level-2 line + release flag on its OWN line; spinners use
//      s_sleep backoff. v7 had arrive-counter and spin-flag on ONE line ->
//      cross-XCD ownership ping-pong (206us kernel @ 8% VALU, 5% HBM).
//  (b) S3: no LDS staging, no per-tile barriers. Wave w: head-quad hq=w&1
//      (P in 64 VGPRs), private rows rg=w>>1 stride 4, plain float4 loads
//      with 1-row prefetch. Row read by 2 waves of same CU -> L1 dedup.
//      4 independent 64-lane butterflies (ILP-4). Epilogue: 128KB LDS stage.
//      __launch_bounds__(512,1): VGPR cap 256 (est ~190), 8 waves/CU.

#define L_SEQ   32768
#define E_DIM   1024
#define NHEAD   8
#define HDIM    128
#define NBLK    256          // one block per CU; co-residency by construction

// direct HBM->LDS (fallback path only)
#define GLD16(gp, lp)                                                   \
  __builtin_amdgcn_global_load_lds(                                     \
      (const __attribute__((address_space(1))) void*)(gp),              \
      (__attribute__((address_space(3))) void*)(lp), 16, 0, 0)

// ---- hierarchical grid barrier ----
// layout (int offsets in bar): [i*32] i=0..7 arrival lines; [256] level-2;
// [320] release flag. All on distinct 128B lines. Zeroed host-side per launch.
__device__ __forceinline__ void gbar(int* bar, int phase)
{
  __syncthreads();
  if (threadIdx.x == 0) {
    int* cnt  = bar + ((blockIdx.x & 7) << 5);
    int* lvl2 = bar + 256;
    int* rel  = bar + 320;
    bool done = false;
    if (__hip_atomic_fetch_add(cnt, 1, __ATOMIC_ACQ_REL,
                               __HIP_MEMORY_SCOPE_AGENT) == 31) {
      if (__hip_atomic_fetch_add(lvl2, 1, __ATOMIC_ACQ_REL,
                                 __HIP_MEMORY_SCOPE_AGENT) == 7) {
        // last arriver: reset counters, then release
#pragma unroll
        for (int i = 0; i < 8; ++i)
          __hip_atomic_store(bar + (i << 5), 0, __ATOMIC_RELAXED,
                             __HIP_MEMORY_SCOPE_AGENT);
        __hip_atomic_store(lvl2, 0, __ATOMIC_RELAXED, __HIP_MEMORY_SCOPE_AGENT);
        __hip_atomic_store(rel, phase, __ATOMIC_RELEASE, __HIP_MEMORY_SCOPE_AGENT);
        done = true;
      }
    }
    if (!done) {
      while (__hip_atomic_load(rel, __ATOMIC_ACQUIRE,
                               __HIP_MEMORY_SCOPE_AGENT) < phase)
        __builtin_amdgcn_s_sleep(2);
    }
  }
  __syncthreads();
}

__global__ __launch_bounds__(512, 1) void mha_all(
    const float* __restrict__ x,   const float* __restrict__ Wi,
    const float* __restrict__ bi,  const float* __restrict__ Wo,
    const float* __restrict__ bo,  float* __restrict__ out,
    float* __restrict__ q,   float* __restrict__ P_T,
    float* __restrict__ zn,  float* __restrict__ attn,
    float* __restrict__ psumw, float* __restrict__ pz,
    int* bar)
{
  __shared__ __align__(16) float smem[8 * 4 * E_DIM];   // 128 KB, reused per stage
  __shared__ __align__(16) float swq[32];               // [wave][j] sum-of-weights
  __shared__ __align__(16) float swst4[8][NHEAD];
  __shared__ float sumw_s[NHEAD];

  const int t    = threadIdx.x;
  const int wave = t >> 6;
  const int lane = t & 63;
  const int bid  = blockIdx.x;

  // ---------------- S1: q = Wq x0 + bq (blocks 0..127, wave-per-output) ----------------
  if (bid < 128) {
    const int o = bid * 8 + wave;
    const float4* Wr = (const float4*)(Wi + (size_t)o * E_DIM);
    const float4* xr = (const float4*)x;           // row 0 of x
    float a = 0.f;
#pragma unroll
    for (int k = 0; k < 4; ++k) {
      float4 wv = Wr[lane + 64 * k];
      float4 xv = xr[lane + 64 * k];
      a += wv.x * xv.x + wv.y * xv.y + wv.z * xv.z + wv.w * xv.w;
    }
#pragma unroll
    for (int m = 1; m < 64; m <<= 1) a += __shfl_xor(a, m, 64);
    if (lane == 0) q[o] = a + bi[o];
  }
  gbar(bar, 1);

  // ---------------- S2: P_T[h][e] = (1/sqrt(D)) Wk_h^T q_h (blocks 0..127) ----------------
  if (bid < 128) {
    float4 (*ps)[16] = (float4(*)[16])smem;        // [32][16] float4 = 8 KB
    const int h   = bid >> 4;
    const int ec2 = bid & 15;                      // 64-wide e-chunk
    const int eg  = t & 15;
    const int dg  = t >> 4;                        // d-group of 4
    const float* Wb = Wi + ((size_t)E_DIM + h * HDIM + dg * 4) * E_DIM + ec2 * 64 + eg * 4;
    const float* qh = q + h * HDIM + dg * 4;
    float4 a = make_float4(0.f, 0.f, 0.f, 0.f);
#pragma unroll
    for (int dd = 0; dd < 4; ++dd) {
      const float qv = qh[dd];
      const float4 wv = *(const float4*)(Wb + (size_t)dd * E_DIM);
      a.x += qv * wv.x; a.y += qv * wv.y; a.z += qv * wv.z; a.w += qv * wv.w;
    }
    ps[dg][eg] = a;
    __syncthreads();
    if (t < 16) {
      float4 s = ps[0][t];
#pragma unroll
      for (int g = 1; g < 32; ++g) {
        const float4 b = ps[g][t];
        s.x += b.x; s.y += b.y; s.z += b.z; s.w += b.w;
      }
      const float sc = 0.08838834764831845f;       // 1/sqrt(128)
      s.x *= sc; s.y *= sc; s.z *= sc; s.w *= sc;
      *(float4*)(P_T + (size_t)h * E_DIM + ec2 * 64 + t * 4) = s;
    }
    __syncthreads();                               // smem reused in S3 epilogue
  }
  gbar(bar, 2);

  // ---------------- S3: scores + softmax-weights + weighted-x, no LDS, no barriers ----------------
  {
    const int hq = wave & 1;                       // head quad: heads 4*hq..4*hq+3
    const int rg = wave >> 1;                      // row group: rows rg, rg+4, ...
    const size_t row0 = (size_t)bid * (L_SEQ / NBLK);   // 128 rows per block

    // P fragments: 4 heads x 16 cols/lane = 64 VGPR
    float4 p[4][4];
#pragma unroll
    for (int j = 0; j < 4; ++j) {
      const float4* P0 = (const float4*)(P_T + (size_t)(4 * hq + j) * E_DIM);
#pragma unroll
      for (int c = 0; c < 4; ++c) p[j][c] = P0[64 * c + lane];
    }

    float4 z[4][4];
#pragma unroll
    for (int j = 0; j < 4; ++j)
#pragma unroll
      for (int c = 0; c < 4; ++c) z[j][c] = make_float4(0.f, 0.f, 0.f, 0.f);
    float sumw[4] = {0.f, 0.f, 0.f, 0.f};

    // preload row k=0
    float4 xr[4];
    {
      const float4* g = (const float4*)(x + (row0 + rg) * E_DIM);
#pragma unroll
      for (int c = 0; c < 4; ++c) xr[c] = g[64 * c + lane];
    }

    for (int k = 0; k < 32; ++k) {
      float4 xn[4];
      if (k < 31) {
        const float4* g = (const float4*)(x + (row0 + rg + 4 * (k + 1)) * E_DIM);
#pragma unroll
        for (int c = 0; c < 4; ++c) xn[c] = g[64 * c + lane];
      }

      float s[4] = {0.f, 0.f, 0.f, 0.f};
#pragma unroll
      for (int j = 0; j < 4; ++j)
#pragma unroll
        for (int c = 0; c < 4; ++c)
          s[j] += xr[c].x * p[j][c].x + xr[c].y * p[j][c].y +
                  xr[c].z * p[j][c].z + xr[c].w * p[j][c].w;

      // 4 independent full butterflies (ILP-4); every lane gets each total
#pragma unroll
      for (int m = 1; m < 64; m <<= 1) {
#pragma unroll
        for (int j = 0; j < 4; ++j) s[j] += __shfl_xor(s[j], m, 64);
      }

      float w[4];
#pragma unroll
      for (int j = 0; j < 4; ++j) { w[j] = __expf(s[j]); sumw[j] += w[j]; }

#pragma unroll
      for (int j = 0; j < 4; ++j)
#pragma unroll
        for (int c = 0; c < 4; ++c) {
          z[j][c].x += w[j] * xr[c].x; z[j][c].y += w[j] * xr[c].y;
          z[j][c].z += w[j] * xr[c].z; z[j][c].w += w[j] * xr[c].w;
        }

      if (k < 31) {
#pragma unroll
        for (int c = 0; c < 4; ++c) xr[c] = xn[c];
      }
    }

    // epilogue: stage all 8 wave-partials in LDS, combine, write pz
    {
      float4* zd = (float4*)(smem + wave * 4096);
#pragma unroll
      for (int j = 0; j < 4; ++j)
#pragma unroll
        for (int c = 0; c < 4; ++c) zd[j * 256 + 64 * c + lane] = z[j][c];
      if (lane == 0) {
#pragma unroll
        for (int j = 0; j < 4; ++j) swq[wave * 4 + j] = sumw[j];
      }
    }
    __syncthreads();
    {
      float* pzb = pz + (size_t)bid * (NHEAD * E_DIM);
#pragma unroll
      for (int m = 0; m < 16; ++m) {
        const int idx = t + 512 * m;               // 0..8191 = h*1024+e
        const int h  = idx >> 10;
        const int e  = idx & 1023;
        const int hh = (h >> 2);                   // hq
        const int j  = h & 3;
        float v = 0.f;
#pragma unroll
        for (int rg2 = 0; rg2 < 4; ++rg2)
          v += smem[(2 * rg2 + hh) * 4096 + j * 1024 + e];
        pzb[idx] = v;
      }
    }
    if (t < NHEAD) {
      const int hh = t >> 2, j = t & 3;
      float s2 = 0.f;
#pragma unroll
      for (int rg2 = 0; rg2 < 4; ++rg2) s2 += swq[(2 * rg2 + hh) * 4 + j];
      psumw[bid * NHEAD + t] = s2;
    }
  }
  gbar(bar, 3);

  // ---------------- S4: zn[h][e] = sum_b pz / sum_b psumw (all blocks) ----------------
  {
    float* red = smem;                             // 512 floats
    float sw[NHEAD];
#pragma unroll
    for (int h = 0; h < NHEAD; ++h) sw[h] = 0.f;
    for (int b2 = t; b2 < NBLK; b2 += 512) {
      const float4* p = (const float4*)(psumw + (size_t)b2 * NHEAD);
      float4 a0 = p[0], a1 = p[1];
      sw[0] += a0.x; sw[1] += a0.y; sw[2] += a0.z; sw[3] += a0.w;
      sw[4] += a1.x; sw[5] += a1.y; sw[6] += a1.z; sw[7] += a1.w;
    }
#pragma unroll
    for (int m = 1; m < 64; m <<= 1) {
#pragma unroll
      for (int h = 0; h < NHEAD; ++h) sw[h] += __shfl_xor(sw[h], m, 64);
    }
    if (lane == 0) {
#pragma unroll
      for (int h = 0; h < NHEAD; ++h) swst4[wave][h] = sw[h];
    }
    __syncthreads();
    if (t < NHEAD) {
      float s = 0.f;
#pragma unroll
      for (int wv = 0; wv < 8; ++wv) s += swst4[wv][t];
      sumw_s[t] = s;
    }

    const int o = bid * 32 + (t & 31);
    const int g = t >> 5;                          // 16 column-groups
    float a = 0.f;
    for (int b2 = g; b2 < NBLK; b2 += 16) a += pz[(size_t)b2 * (NHEAD * E_DIM) + o];
    red[t] = a;
    __syncthreads();
    if (t < 32) {
      float s2 = 0.f;
#pragma unroll
      for (int gg = 0; gg < 16; ++gg) s2 += red[gg * 32 + t];
      const int oo = bid * 32 + t;
      zn[oo] = s2 / sumw_s[oo >> 10];              // oo = h*1024 + e
    }
  }
  gbar(bar, 4);

  // ---------------- S5: attn[o] = Wv[o] . zn[h(o)] + bv[o] (blocks 0..127) ----------------
  if (bid < 128) {
    const int o = bid * 8 + wave;
    const float4* Wr = (const float4*)(Wi + ((size_t)2 * E_DIM + o) * E_DIM);
    const float4* zr = (const float4*)(zn + (size_t)(o >> 7) * E_DIM);
    float a = 0.f;
#pragma unroll
    for (int k = 0; k < 4; ++k) {
      float4 wv = Wr[lane + 64 * k];
      float4 zv = zr[lane + 64 * k];
      a += wv.x * zv.x + wv.y * zv.y + wv.z * zv.z + wv.w * zv.w;
    }
#pragma unroll
    for (int m = 1; m < 64; m <<= 1) a += __shfl_xor(a, m, 64);
    if (lane == 0) attn[o] = a + bi[2 * E_DIM + o];
  }
  gbar(bar, 5);

  // ---------------- S6: out[e] = Wo[e] . attn + bo[e] (blocks 0..127) ----------------
  if (bid < 128) {
    const int o = bid * 8 + wave;
    const float4* Wr = (const float4*)(Wo + (size_t)o * E_DIM);
    const float4* vr = (const float4*)attn;
    float a = 0.f;
#pragma unroll
    for (int k = 0; k < 4; ++k) {
      float4 wv = Wr[lane + 64 * k];
      float4 vv = vr[lane + 64 * k];
      a += wv.x * vv.x + wv.y * vv.y + wv.z * vv.z + wv.w * vv.w;
    }
#pragma unroll
    for (int m = 1; m < 64; m <<= 1) a += __shfl_xor(a, m, 64);
    if (lane == 0) out[o] = a + bo[o];
  }
}

// ================= fallback multi-kernel path (used only if ws too small) =================

__global__ __launch_bounds__(256) void proj_q(
    const float* __restrict__ W, const float* __restrict__ bias,
    const float* __restrict__ x, float* __restrict__ q)
{
  const int t = threadIdx.x, wave = t >> 6, lane = t & 63;
  const int o = blockIdx.x * 4 + wave;
  const float4* Wr = (const float4*)(W + (size_t)o * E_DIM);
  const float4* xr = (const float4*)x;
  float a = 0.f;
#pragma unroll
  for (int k = 0; k < 4; ++k) {
    float4 wv = Wr[lane + 64 * k];
    float4 xv = xr[lane + 64 * k];
    a += wv.x * xv.x + wv.y * xv.y + wv.z * xv.z + wv.w * xv.w;
  }
#pragma unroll
  for (int m = 1; m < 64; m <<= 1) a += __shfl_xor(a, m, 64);
  if (lane == 0) q[o] = a + bias[o];
}

__global__ __launch_bounds__(128) void make_p(
    const float* __restrict__ W, const float* __restrict__ q,
    float* __restrict__ P_T)
{
  const int h = blockIdx.y;
  const int e = blockIdx.x * 128 + threadIdx.x;
  const float* qh = q + h * HDIM;
  const float* Wb = W + ((size_t)E_DIM + (size_t)h * HDIM) * E_DIM + e;
  float a0 = 0.f, a1 = 0.f, a2 = 0.f, a3 = 0.f;
#pragma unroll 4
  for (int d = 0; d < HDIM; d += 4) {
    a0 += qh[d + 0] * Wb[(size_t)(d + 0) * E_DIM];
    a1 += qh[d + 1] * Wb[(size_t)(d + 1) * E_DIM];
    a2 += qh[d + 2] * Wb[(size_t)(d + 2) * E_DIM];
    a3 += qh[d + 3] * Wb[(size_t)(d + 3) * E_DIM];
  }
  P_T[h * E_DIM + e] = ((a0 + a1) + (a2 + a3)) * 0.08838834764831845f;
}

__global__ __launch_bounds__(512, 2) void attn_fused5(
    const float* __restrict__ x, const float* __restrict__ P_T,
    float* __restrict__ partial_z, float* __restrict__ partial_sumw,
    int rows_per_blk)
{
  __shared__ __align__(16) float sbuf[2][8][E_DIM];
  __shared__ float swst[16];
  const int t = threadIdx.x, wave = t >> 6, lane = t & 63;
  const int rh = wave >> 2, h0 = (wave & 3) * 2;
  const size_t row0 = (size_t)blockIdx.x * rows_per_blk;
  const int ntiles = rows_per_blk / 8;

  float4 p0[4], p1[4];
  {
    const float4* P0 = (const float4*)(P_T + (size_t)h0 * E_DIM);
    const float4* P1 = (const float4*)(P_T + (size_t)(h0 + 1) * E_DIM);
#pragma unroll
    for (int k = 0; k < 4; ++k) { p0[k] = P0[64 * k + lane]; p1[k] = P1[64 * k + lane]; }
  }
  float4 z0[4], z1[4];
#pragma unroll
  for (int k = 0; k < 4; ++k) {
    z0[k] = make_float4(0.f, 0.f, 0.f, 0.f);
    z1[k] = make_float4(0.f, 0.f, 0.f, 0.f);
  }
  float sumw0 = 0.f, sumw1 = 0.f;
  {
    const float* g = x + (row0 + wave) * E_DIM + 4 * lane;
#pragma unroll
    for (int k = 0; k < 4; ++k) GLD16(g + k * 256, &sbuf[0][wave][k * 256]);
  }
  __syncthreads();
  for (int tile = 0; tile < ntiles; ++tile) {
    const int buf = tile & 1;
    if (tile + 1 < ntiles) {
      const float* g = x + (row0 + (size_t)(tile + 1) * 8 + wave) * E_DIM + 4 * lane;
#pragma unroll
      for (int k = 0; k < 4; ++k) GLD16(g + k * 256, &sbuf[buf ^ 1][wave][k * 256]);
    }
#pragma unroll
    for (int rl = 0; rl < 4; ++rl) {
      const float4* xr4 = (const float4*)&sbuf[buf][rh * 4 + rl][0];
      float4 xr[4];
#pragma unroll
      for (int k = 0; k < 4; ++k) xr[k] = xr4[64 * k + lane];
      float s0 = 0.f, s1 = 0.f;
#pragma unroll
      for (int k = 0; k < 4; ++k) {
        s0 += xr[k].x * p0[k].x + xr[k].y * p0[k].y + xr[k].z * p0[k].z + xr[k].w * p0[k].w;
        s1 += xr[k].x * p1[k].x + xr[k].y * p1[k].y + xr[k].z * p1[k].z + xr[k].w * p1[k].w;
      }
      const bool odd = (lane & 1);
      float keep = odd ? s1 : s0;
      float oth  = odd ? s0 : s1;
      float ts = keep + __shfl_xor(oth, 1, 64);
      ts += __shfl_xor(ts, 2, 64);
      ts += __shfl_xor(ts, 4, 64);
      ts += __shfl_xor(ts, 8, 64);
      ts += __shfl_xor(ts, 16, 64);
      ts += __shfl_xor(ts, 32, 64);
      const float ex = __expf(ts);
      const float ox = __shfl_xor(ex, 1, 64);
      const float w0 = odd ? ox : ex;
      const float w1 = odd ? ex : ox;
      sumw0 += w0; sumw1 += w1;
#pragma unroll
      for (int k = 0; k < 4; ++k) {
        z0[k].x += w0 * xr[k].x; z0[k].y += w0 * xr[k].y;
        z0[k].z += w0 * xr[k].z; z0[k].w += w0 * xr[k].w;
        z1[k].x += w1 * xr[k].x; z1[k].y += w1 * xr[k].y;
        z1[k].z += w1 * xr[k].z; z1[k].w += w1 * xr[k].w;
      }
    }
    __syncthreads();
  }
  float (*zs)[E_DIM] = (float(*)[E_DIM])&sbuf[0][0][0];
  {
    float4* zd0 = (float4*)&zs[2 * wave][0];
    float4* zd1 = (float4*)&zs[2 * wave + 1][0];
#pragma unroll
    for (int k = 0; k < 4; ++k) { zd0[64 * k + lane] = z0[k]; zd1[64 * k + lane] = z1[k]; }
  }
  if (lane == 0) { swst[2 * wave] = sumw0; swst[2 * wave + 1] = sumw1; }
  __syncthreads();
  {
    const float4* zsv = (const float4*)&zs[0][0];
    float4* pzb = (float4*)(partial_z + (size_t)blockIdx.x * (NHEAD * E_DIM));
#pragma unroll
    for (int j = 0; j < 4; ++j) {
      const int idx = t + 512 * j;
      const float4 a = zsv[idx], b = zsv[idx + 2048];
      pzb[idx] = make_float4(a.x + b.x, a.y + b.y, a.z + b.z, a.w + b.w);
    }
  }
  if (t < NHEAD)
    partial_sumw[blockIdx.x * NHEAD + t] = swst[t] + swst[t + 8];
}

__global__ __launch_bounds__(256) void reduce_z(
    const float* __restrict__ partial_z, const float* __restrict__ partial_sumw,
    float* __restrict__ zn, int nblk)
{
  __shared__ float red[256];
  __shared__ __align__(16) float swst[4][NHEAD];
  __shared__ float sumw_s[NHEAD];
  const int t = threadIdx.x;
  const int lane = t & 63, wave = t >> 6;
  float sw[NHEAD];
#pragma unroll
  for (int h = 0; h < NHEAD; ++h) sw[h] = 0.f;
  for (int b = t; b < nblk; b += 256) {
    const float4* p = (const float4*)(partial_sumw + (size_t)b * NHEAD);
    float4 a0 = p[0], a1 = p[1];
    sw[0] += a0.x; sw[1] += a0.y; sw[2] += a0.z; sw[3] += a0.w;
    sw[4] += a1.x; sw[5] += a1.y; sw[6] += a1.z; sw[7] += a1.w;
  }
#pragma unroll
  for (int m = 1; m < 64; m <<= 1) {
#pragma unroll
    for (int h = 0; h < NHEAD; ++h) sw[h] += __shfl_xor(sw[h], m, 64);
  }
  if (lane == 0) {
#pragma unroll
    for (int h = 0; h < NHEAD; ++h) swst[wave][h] = sw[h];
  }
  __syncthreads();
  if (t < NHEAD) sumw_s[t] = swst[0][t] + swst[1][t] + swst[2][t] + swst[3][t];
  const int o = blockIdx.x * 32 + (t & 31);
  const int g = t >> 5;
  float a = 0.f;
  for (int b = g; b < nblk; b += 8) a += partial_z[(size_t)b * (NHEAD * E_DIM) + o];
  red[t] = a;
  __syncthreads();
  if (t < 32) {
    float s2 = 0.f;
#pragma unroll
    for (int gg = 0; gg < 8; ++gg) s2 += red[gg * 32 + t];
    const int oo = blockIdx.x * 32 + t;
    zn[oo] = s2 / sumw_s[oo >> 10];
  }
}

__global__ __launch_bounds__(256) void proj_v(
    const float* __restrict__ W, const float* __restrict__ bias,
    const float* __restrict__ zn, float* __restrict__ attn)
{
  const int t = threadIdx.x, wave = t >> 6, lane = t & 63;
  const int o = blockIdx.x * 4 + wave;
  const float4* Wr = (const float4*)(W + ((size_t)2 * E_DIM + o) * E_DIM);
  const float4* zr = (const float4*)(zn + (size_t)(o >> 7) * E_DIM);
  float a = 0.f;
#pragma unroll
  for (int k = 0; k < 4; ++k) {
    float4 wv = Wr[lane + 64 * k];
    float4 zv = zr[lane + 64 * k];
    a += wv.x * zv.x + wv.y * zv.y + wv.z * zv.z + wv.w * zv.w;
  }
#pragma unroll
  for (int m = 1; m < 64; m <<= 1) a += __shfl_xor(a, m, 64);
  if (lane == 0) attn[o] = a + bias[2 * E_DIM + o];
}

__global__ __launch_bounds__(256) void proj_o(
    const float* __restrict__ Wo, const float* __restrict__ bo,
    const float* __restrict__ attn, float* __restrict__ out)
{
  const int t = threadIdx.x, wave = t >> 6, lane = t & 63;
  const int o = blockIdx.x * 4 + wave;
  const float4* Wr = (const float4*)(Wo + (size_t)o * E_DIM);
  const float4* vr = (const float4*)attn;
  float a = 0.f;
#pragma unroll
  for (int k = 0; k < 4; ++k) {
    float4 wv = Wr[lane + 64 * k];
    float4 vv = vr[lane + 64 * k];
    a += wv.x * vv.x + wv.y * vv.y + wv.z * vv.z + wv.w * vv.w;
  }
#pragma unroll
  for (int m = 1; m < 64; m <<= 1) a += __shfl_xor(a, m, 64);
  if (lane == 0) out[o] = a + bo[o];
}

extern "C" void kernel_launch(void* const* d_in, const int* in_sizes, int n_in,
                              void* d_out, int out_size, void* d_ws, size_t ws_size,
                              hipStream_t stream)
{
  const float* x  = (const float*)d_in[0];   // [32768,1024]
  const float* Wi = (const float*)d_in[1];   // [3072,1024]
  const float* bi = (const float*)d_in[2];   // [3072]
  const float* Wo = (const float*)d_in[3];   // [1024,1024]
  const float* bo = (const float*)d_in[4];   // [1024]
  float* out = (float*)d_out;                // [1024] fp32

  // workspace layout (bytes)
  char* ws = (char*)d_ws;
  float* q     = (float*)(ws + 0);           // 1024 f
  float* P_T   = (float*)(ws + 4096);        // 8192 f
  float* zn    = (float*)(ws + 36864);       // 8192 f
  float* attn  = (float*)(ws + 69632);       // 1024 f
  float* psumw = (float*)(ws + 73728);       // nblk*8 f
  int*   bar   = (int*)  (ws + 81920);       // barrier lines (1.3 KB)
  const size_t pz_off = 90112;
  float* pz    = (float*)(ws + pz_off);      // nblk*8192 f

  const size_t need_coop = pz_off + (size_t)NBLK * NHEAD * E_DIM * 4;
  if (ws_size >= need_coop) {
    hipMemsetAsync(bar, 0, 2048, stream);    // zero barrier lines
    mha_all<<<NBLK, 512, 0, stream>>>(x, Wi, bi, Wo, bo, out,
                                      q, P_T, zn, attn, psumw, pz, bar);
    return;
  }

  // fallback (small workspace): 6-dispatch pipeline
  int nblk = 128;
  if (ws_size >= pz_off + (size_t)512 * NHEAD * E_DIM * 4) nblk = 512;
  else if (ws_size >= pz_off + (size_t)256 * NHEAD * E_DIM * 4) nblk = 256;
  const int rows_per_blk = L_SEQ / nblk;

  proj_q     <<<256, 256, 0, stream>>>(Wi, bi, x, q);
  make_p     <<<dim3(8, 8), 128, 0, stream>>>(Wi, q, P_T);
  attn_fused5<<<nblk, 512, 0, stream>>>(x, P_T, pz, psumw, rows_per_blk);
  reduce_z   <<<256, 256, 0, stream>>>(pz, psumw, zn, nblk);
  proj_v     <<<256, 256, 0, stream>>>(Wi, bi, zn, attn);
  proj_o     <<<256, 256, 0, stream>>>(Wo, bo, attn, out);
}

// Round 5
// 299.883 us; speedup vs baseline: 1.1704x; 1.1019x over previous
//
#include <hip/hip_runtime.h>
#include <math.h>

// Single-query MHA, algebraically collapsed:
//   s[l,h] = x_l . p_h   (p_h = Wk_h^T q_h / sqrt(D); k-bias shift cancels in softmax)
//   z_h    = sum_l softmax(s)_lh * x_l ;  attn = Wv z + bv ; out = Wo attn + bo
//
// v9: single-dispatch, barrier POLL fixed. v8 post-mortem: kernel 186us with
// VALU 9%/HBM 6% -> stall-bound. v7->v8 changed arrival contention only; both
// polled with ACQUIRE agent loads = cache-invalidate per poll x 250 blocks x
// whole wait = fabric storm. v9 uses the canonical grid.sync pattern:
//   threadfence() ; relaxed hierarchical adds ; relaxed poll + s_sleep ;
//   release flag store ; threadfence() on exit.   (2 cache ops/block/barrier)
// Also: S1+S2 fused per-head (8 blocks: q_h in LDS -> P_T[h]) = 4 barriers,
// and S3 prefetch depth 2 to cover L3 latency at 2 waves/SIMD.

#define L_SEQ   32768
#define E_DIM   1024
#define NHEAD   8
#define HDIM    128
#define NBLK    256          // one block per CU; co-residency by construction

// direct HBM->LDS (fallback path only)
#define GLD16(gp, lp)                                                   \
  __builtin_amdgcn_global_load_lds(                                     \
      (const __attribute__((address_space(1))) void*)(gp),              \
      (__attribute__((address_space(3))) void*)(lp), 16, 0, 0)

// ---- grid barrier, relaxed-poll version ----
// bar int offsets: [i*32] i=0..7 arrival lines; [256] level-2; [320] release.
// All on distinct 128B lines. Zeroed host-side before launch.
__device__ __forceinline__ void gbar(int* bar, int phase)
{
  __syncthreads();
  if (threadIdx.x == 0) {
    __threadfence();                                   // release: flush L2 writes
    int* cnt  = bar + ((blockIdx.x & 7) << 5);
    int* lvl2 = bar + 256;
    int* rel  = bar + 320;
    bool last = false;
    if (__hip_atomic_fetch_add(cnt, 1, __ATOMIC_RELAXED,
                               __HIP_MEMORY_SCOPE_AGENT) == 31) {
      if (__hip_atomic_fetch_add(lvl2, 1, __ATOMIC_RELAXED,
                                 __HIP_MEMORY_SCOPE_AGENT) == 7) {
        __threadfence();                               // acquire others' arrivals
#pragma unroll
        for (int i = 0; i < 8; ++i)
          __hip_atomic_store(bar + (i << 5), 0, __ATOMIC_RELAXED,
                             __HIP_MEMORY_SCOPE_AGENT);
        __hip_atomic_store(lvl2, 0, __ATOMIC_RELAXED, __HIP_MEMORY_SCOPE_AGENT);
        __hip_atomic_store(rel, phase, __ATOMIC_RELEASE,
                           __HIP_MEMORY_SCOPE_AGENT);  // orders resets before flag
        last = true;
      }
    }
    if (!last) {
      while (__hip_atomic_load(rel, __ATOMIC_RELAXED,
                               __HIP_MEMORY_SCOPE_AGENT) < phase)
        __builtin_amdgcn_s_sleep(4);
    }
    __threadfence();                                   // acquire: inv stale caches
  }
  __syncthreads();
}

__global__ __launch_bounds__(512, 1) void mha_all(
    const float* __restrict__ x,   const float* __restrict__ Wi,
    const float* __restrict__ bi,  const float* __restrict__ Wo,
    const float* __restrict__ bo,  float* __restrict__ out,
    float* __restrict__ P_T, float* __restrict__ zn,
    float* __restrict__ attn, float* __restrict__ psumw,
    float* __restrict__ pz, int* bar)
{
  __shared__ __align__(16) float smem[8 * 4 * E_DIM];   // 128 KB, reused per stage
  __shared__ __align__(16) float swq[32];               // [wave][j] sum-of-weights
  __shared__ __align__(16) float swst4[8][NHEAD];
  __shared__ float sumw_s[NHEAD];

  const int t    = threadIdx.x;
  const int wave = t >> 6;
  const int lane = t & 63;
  const int bid  = blockIdx.x;

  // ------- S1+S2 (blocks 0..7, one head each): q_h -> LDS, then P_T[h][:] -------
  if (bid < NHEAD) {
    const int h = bid;
    float* q_lds = smem;                               // 128 floats

    // Stage A: q_h[o'] = Wq[h*128+o'] . x0 + bq ; x row0 held in registers
    float4 x0[4];
    {
      const float4* xr0 = (const float4*)x;
#pragma unroll
      for (int c = 0; c < 4; ++c) x0[c] = xr0[64 * c + lane];
    }
#pragma unroll
    for (int i = 0; i < 16; ++i) {
      const int op = wave * 16 + i;                    // 0..127
      const int o  = h * HDIM + op;
      const float4* Wr = (const float4*)(Wi + (size_t)o * E_DIM);
      float a = 0.f;
#pragma unroll
      for (int c = 0; c < 4; ++c) {
        float4 wv = Wr[64 * c + lane];
        a += wv.x * x0[c].x + wv.y * x0[c].y + wv.z * x0[c].z + wv.w * x0[c].w;
      }
#pragma unroll
      for (int m = 1; m < 64; m <<= 1) a += __shfl_xor(a, m, 64);
      if (lane == 0) q_lds[op] = a + bi[o];
    }
    __syncthreads();

    // Stage B: P_T[h][e] = (1/sqrt(D)) sum_d q_h[d] * Wk[h*128+d][e]
    // thread t owns cols {2t, 2t+1}; per d: coalesced 4KB row read
    float acc0 = 0.f, acc1 = 0.f;
    const float* Wk = Wi + ((size_t)E_DIM + (size_t)h * HDIM) * E_DIM;
#pragma unroll 4
    for (int d = 0; d < HDIM; ++d) {
      const float qv = q_lds[d];                       // lane-uniform broadcast
      const float2 wv = *(const float2*)(Wk + (size_t)d * E_DIM + 2 * t);
      acc0 += qv * wv.x; acc1 += qv * wv.y;
    }
    const float sc = 0.08838834764831845f;             // 1/sqrt(128)
    *(float2*)(P_T + (size_t)h * E_DIM + 2 * t) = make_float2(acc0 * sc, acc1 * sc);
    __syncthreads();                                   // smem reused later
  }
  gbar(bar, 1);

  // ------- S3: scores + softmax-weights + weighted-x (all blocks) -------
  {
    const int hq = wave & 1;                           // head quad: 4*hq..4*hq+3
    const int rg = wave >> 1;                          // rows rg, rg+4, ...
    const size_t row0 = (size_t)bid * (L_SEQ / NBLK);  // 128 rows per block

    float4 p[4][4];                                    // 4 heads x 16 cols/lane
#pragma unroll
    for (int j = 0; j < 4; ++j) {
      const float4* P0 = (const float4*)(P_T + (size_t)(4 * hq + j) * E_DIM);
#pragma unroll
      for (int c = 0; c < 4; ++c) p[j][c] = P0[64 * c + lane];
    }

    float4 z[4][4];
#pragma unroll
    for (int j = 0; j < 4; ++j)
#pragma unroll
      for (int c = 0; c < 4; ++c) z[j][c] = make_float4(0.f, 0.f, 0.f, 0.f);
    float sumw[4] = {0.f, 0.f, 0.f, 0.f};

    // 2-deep prefetch: rows k and k+1 in registers
    float4 xa[4], xb[4];
    {
      const float4* g0 = (const float4*)(x + (row0 + rg) * E_DIM);
      const float4* g1 = (const float4*)(x + (row0 + rg + 4) * E_DIM);
#pragma unroll
      for (int c = 0; c < 4; ++c) { xa[c] = g0[64 * c + lane]; xb[c] = g1[64 * c + lane]; }
    }

#pragma unroll 2
    for (int k = 0; k < 32; ++k) {
      float4 xn[4];
      if (k < 30) {
        const float4* g = (const float4*)(x + (row0 + rg + 4 * (k + 2)) * E_DIM);
#pragma unroll
        for (int c = 0; c < 4; ++c) xn[c] = g[64 * c + lane];
      }

      float s[4] = {0.f, 0.f, 0.f, 0.f};
#pragma unroll
      for (int j = 0; j < 4; ++j)
#pragma unroll
        for (int c = 0; c < 4; ++c)
          s[j] += xa[c].x * p[j][c].x + xa[c].y * p[j][c].y +
                  xa[c].z * p[j][c].z + xa[c].w * p[j][c].w;

#pragma unroll
      for (int m = 1; m < 64; m <<= 1) {
#pragma unroll
        for (int j = 0; j < 4; ++j) s[j] += __shfl_xor(s[j], m, 64);
      }

      float w[4];
#pragma unroll
      for (int j = 0; j < 4; ++j) { w[j] = __expf(s[j]); sumw[j] += w[j]; }

#pragma unroll
      for (int j = 0; j < 4; ++j)
#pragma unroll
        for (int c = 0; c < 4; ++c) {
          z[j][c].x += w[j] * xa[c].x; z[j][c].y += w[j] * xa[c].y;
          z[j][c].z += w[j] * xa[c].z; z[j][c].w += w[j] * xa[c].w;
        }

#pragma unroll
      for (int c = 0; c < 4; ++c) { xa[c] = xb[c]; xb[c] = xn[c]; }
    }

    // epilogue: stage wave partials in LDS, combine, write pz
    {
      float4* zd = (float4*)(smem + wave * 4096);
#pragma unroll
      for (int j = 0; j < 4; ++j)
#pragma unroll
        for (int c = 0; c < 4; ++c) zd[j * 256 + 64 * c + lane] = z[j][c];
      if (lane == 0) {
#pragma unroll
        for (int j = 0; j < 4; ++j) swq[wave * 4 + j] = sumw[j];
      }
    }
    __syncthreads();
    {
      float* pzb = pz + (size_t)bid * (NHEAD * E_DIM);
#pragma unroll
      for (int m = 0; m < 16; ++m) {
        const int idx = t + 512 * m;                   // 0..8191 = h*1024+e
        const int h  = idx >> 10;
        const int e  = idx & 1023;
        const int hh = h >> 2;                         // hq
        const int j  = h & 3;
        float v = 0.f;
#pragma unroll
        for (int rg2 = 0; rg2 < 4; ++rg2)
          v += smem[(2 * rg2 + hh) * 4096 + j * 1024 + e];
        pzb[idx] = v;
      }
    }
    if (t < NHEAD) {
      const int hh = t >> 2, j = t & 3;
      float s2 = 0.f;
#pragma unroll
      for (int rg2 = 0; rg2 < 4; ++rg2) s2 += swq[(2 * rg2 + hh) * 4 + j];
      psumw[bid * NHEAD + t] = s2;
    }
  }
  gbar(bar, 2);

  // ------- S4: zn[h][e] = sum_b pz / sum_b psumw (all blocks) -------
  {
    float* red = smem;                                 // 512 floats
    float sw[NHEAD];
#pragma unroll
    for (int h = 0; h < NHEAD; ++h) sw[h] = 0.f;
    for (int b2 = t; b2 < NBLK; b2 += 512) {
      const float4* p = (const float4*)(psumw + (size_t)b2 * NHEAD);
      float4 a0 = p[0], a1 = p[1];
      sw[0] += a0.x; sw[1] += a0.y; sw[2] += a0.z; sw[3] += a0.w;
      sw[4] += a1.x; sw[5] += a1.y; sw[6] += a1.z; sw[7] += a1.w;
    }
#pragma unroll
    for (int m = 1; m < 64; m <<= 1) {
#pragma unroll
      for (int h = 0; h < NHEAD; ++h) sw[h] += __shfl_xor(sw[h], m, 64);
    }
    if (lane == 0) {
#pragma unroll
      for (int h = 0; h < NHEAD; ++h) swst4[wave][h] = sw[h];
    }
    __syncthreads();
    if (t < NHEAD) {
      float s = 0.f;
#pragma unroll
      for (int wv = 0; wv < 8; ++wv) s += swst4[wv][t];
      sumw_s[t] = s;
    }

    const int o = bid * 32 + (t & 31);
    const int g = t >> 5;                              // 16 column-groups
    float a = 0.f;
    for (int b2 = g; b2 < NBLK; b2 += 16) a += pz[(size_t)b2 * (NHEAD * E_DIM) + o];
    red[t] = a;
    __syncthreads();
    if (t < 32) {
      float s2 = 0.f;
#pragma unroll
      for (int gg = 0; gg < 16; ++gg) s2 += red[gg * 32 + t];
      const int oo = bid * 32 + t;
      zn[oo] = s2 / sumw_s[oo >> 10];                  // oo = h*1024 + e
    }
  }
  gbar(bar, 3);

  // ------- S5: attn[o] = Wv[o] . zn[h(o)] + bv[o] (blocks 0..127) -------
  if (bid < 128) {
    const int o = bid * 8 + wave;
    const float4* Wr = (const float4*)(Wi + ((size_t)2 * E_DIM + o) * E_DIM);
    const float4* zr = (const float4*)(zn + (size_t)(o >> 7) * E_DIM);
    float a = 0.f;
#pragma unroll
    for (int k = 0; k < 4; ++k) {
      float4 wv = Wr[lane + 64 * k];
      float4 zv = zr[lane + 64 * k];
      a += wv.x * zv.x + wv.y * zv.y + wv.z * zv.z + wv.w * zv.w;
    }
#pragma unroll
    for (int m = 1; m < 64; m <<= 1) a += __shfl_xor(a, m, 64);
    if (lane == 0) attn[o] = a + bi[2 * E_DIM + o];
  }
  gbar(bar, 4);

  // ------- S6: out[e] = Wo[e] . attn + bo[e] (blocks 0..127) -------
  if (bid < 128) {
    const int o = bid * 8 + wave;
    const float4* Wr = (const float4*)(Wo + (size_t)o * E_DIM);
    const float4* vr = (const float4*)attn;
    float a = 0.f;
#pragma unroll
    for (int k = 0; k < 4; ++k) {
      float4 wv = Wr[lane + 64 * k];
      float4 vv = vr[lane + 64 * k];
      a += wv.x * vv.x + wv.y * vv.y + wv.z * vv.z + wv.w * vv.w;
    }
#pragma unroll
    for (int m = 1; m < 64; m <<= 1) a += __shfl_xor(a, m, 64);
    if (lane == 0) out[o] = a + bo[o];
  }
}

// ================= fallback multi-kernel path (used only if ws too small) =================

__global__ __launch_bounds__(256) void proj_q(
    const float* __restrict__ W, const float* __restrict__ bias,
    const float* __restrict__ x, float* __restrict__ q)
{
  const int t = threadIdx.x, wave = t >> 6, lane = t & 63;
  const int o = blockIdx.x * 4 + wave;
  const float4* Wr = (const float4*)(W + (size_t)o * E_DIM);
  const float4* xr = (const float4*)x;
  float a = 0.f;
#pragma unroll
  for (int k = 0; k < 4; ++k) {
    float4 wv = Wr[lane + 64 * k];
    float4 xv = xr[lane + 64 * k];
    a += wv.x * xv.x + wv.y * xv.y + wv.z * xv.z + wv.w * xv.w;
  }
#pragma unroll
  for (int m = 1; m < 64; m <<= 1) a += __shfl_xor(a, m, 64);
  if (lane == 0) q[o] = a + bias[o];
}

__global__ __launch_bounds__(128) void make_p(
    const float* __restrict__ W, const float* __restrict__ q,
    float* __restrict__ P_T)
{
  const int h = blockIdx.y;
  const int e = blockIdx.x * 128 + threadIdx.x;
  const float* qh = q + h * HDIM;
  const float* Wb = W + ((size_t)E_DIM + (size_t)h * HDIM) * E_DIM + e;
  float a0 = 0.f, a1 = 0.f, a2 = 0.f, a3 = 0.f;
#pragma unroll 4
  for (int d = 0; d < HDIM; d += 4) {
    a0 += qh[d + 0] * Wb[(size_t)(d + 0) * E_DIM];
    a1 += qh[d + 1] * Wb[(size_t)(d + 1) * E_DIM];
    a2 += qh[d + 2] * Wb[(size_t)(d + 2) * E_DIM];
    a3 += qh[d + 3] * Wb[(size_t)(d + 3) * E_DIM];
  }
  P_T[h * E_DIM + e] = ((a0 + a1) + (a2 + a3)) * 0.08838834764831845f;
}

__global__ __launch_bounds__(512, 2) void attn_fused5(
    const float* __restrict__ x, const float* __restrict__ P_T,
    float* __restrict__ partial_z, float* __restrict__ partial_sumw,
    int rows_per_blk)
{
  __shared__ __align__(16) float sbuf[2][8][E_DIM];
  __shared__ float swst[16];
  const int t = threadIdx.x, wave = t >> 6, lane = t & 63;
  const int rh = wave >> 2, h0 = (wave & 3) * 2;
  const size_t row0 = (size_t)blockIdx.x * rows_per_blk;
  const int ntiles = rows_per_blk / 8;

  float4 p0[4], p1[4];
  {
    const float4* P0 = (const float4*)(P_T + (size_t)h0 * E_DIM);
    const float4* P1 = (const float4*)(P_T + (size_t)(h0 + 1) * E_DIM);
#pragma unroll
    for (int k = 0; k < 4; ++k) { p0[k] = P0[64 * k + lane]; p1[k] = P1[64 * k + lane]; }
  }
  float4 z0[4], z1[4];
#pragma unroll
  for (int k = 0; k < 4; ++k) {
    z0[k] = make_float4(0.f, 0.f, 0.f, 0.f);
    z1[k] = make_float4(0.f, 0.f, 0.f, 0.f);
  }
  float sumw0 = 0.f, sumw1 = 0.f;
  {
    const float* g = x + (row0 + wave) * E_DIM + 4 * lane;
#pragma unroll
    for (int k = 0; k < 4; ++k) GLD16(g + k * 256, &sbuf[0][wave][k * 256]);
  }
  __syncthreads();
  for (int tile = 0; tile < ntiles; ++tile) {
    const int buf = tile & 1;
    if (tile + 1 < ntiles) {
      const float* g = x + (row0 + (size_t)(tile + 1) * 8 + wave) * E_DIM + 4 * lane;
#pragma unroll
      for (int k = 0; k < 4; ++k) GLD16(g + k * 256, &sbuf[buf ^ 1][wave][k * 256]);
    }
#pragma unroll
    for (int rl = 0; rl < 4; ++rl) {
      const float4* xr4 = (const float4*)&sbuf[buf][rh * 4 + rl][0];
      float4 xr[4];
#pragma unroll
      for (int k = 0; k < 4; ++k) xr[k] = xr4[64 * k + lane];
      float s0 = 0.f, s1 = 0.f;
#pragma unroll
      for (int k = 0; k < 4; ++k) {
        s0 += xr[k].x * p0[k].x + xr[k].y * p0[k].y + xr[k].z * p0[k].z + xr[k].w * p0[k].w;
        s1 += xr[k].x * p1[k].x + xr[k].y * p1[k].y + xr[k].z * p1[k].z + xr[k].w * p1[k].w;
      }
      const bool odd = (lane & 1);
      float keep = odd ? s1 : s0;
      float oth  = odd ? s0 : s1;
      float ts = keep + __shfl_xor(oth, 1, 64);
      ts += __shfl_xor(ts, 2, 64);
      ts += __shfl_xor(ts, 4, 64);
      ts += __shfl_xor(ts, 8, 64);
      ts += __shfl_xor(ts, 16, 64);
      ts += __shfl_xor(ts, 32, 64);
      const float ex = __expf(ts);
      const float ox = __shfl_xor(ex, 1, 64);
      const float w0 = odd ? ox : ex;
      const float w1 = odd ? ex : ox;
      sumw0 += w0; sumw1 += w1;
#pragma unroll
      for (int k = 0; k < 4; ++k) {
        z0[k].x += w0 * xr[k].x; z0[k].y += w0 * xr[k].y;
        z0[k].z += w0 * xr[k].z; z0[k].w += w0 * xr[k].w;
        z1[k].x += w1 * xr[k].x; z1[k].y += w1 * xr[k].y;
        z1[k].z += w1 * xr[k].z; z1[k].w += w1 * xr[k].w;
      }
    }
    __syncthreads();
  }
  float (*zs)[E_DIM] = (float(*)[E_DIM])&sbuf[0][0][0];
  {
    float4* zd0 = (float4*)&zs[2 * wave][0];
    float4* zd1 = (float4*)&zs[2 * wave + 1][0];
#pragma unroll
    for (int k = 0; k < 4; ++k) { zd0[64 * k + lane] = z0[k]; zd1[64 * k + lane] = z1[k]; }
  }
  if (lane == 0) { swst[2 * wave] = sumw0; swst[2 * wave + 1] = sumw1; }
  __syncthreads();
  {
    const float4* zsv = (const float4*)&zs[0][0];
    float4* pzb = (float4*)(partial_z + (size_t)blockIdx.x * (NHEAD * E_DIM));
#pragma unroll
    for (int j = 0; j < 4; ++j) {
      const int idx = t + 512 * j;
      const float4 a = zsv[idx], b = zsv[idx + 2048];
      pzb[idx] = make_float4(a.x + b.x, a.y + b.y, a.z + b.z, a.w + b.w);
    }
  }
  if (t < NHEAD)
    partial_sumw[blockIdx.x * NHEAD + t] = swst[t] + swst[t + 8];
}

__global__ __launch_bounds__(256) void reduce_z(
    const float* __restrict__ partial_z, const float* __restrict__ partial_sumw,
    float* __restrict__ zn, int nblk)
{
  __shared__ float red[256];
  __shared__ __align__(16) float swst[4][NHEAD];
  __shared__ float sumw_s[NHEAD];
  const int t = threadIdx.x;
  const int lane = t & 63, wave = t >> 6;
  float sw[NHEAD];
#pragma unroll
  for (int h = 0; h < NHEAD; ++h) sw[h] = 0.f;
  for (int b = t; b < nblk; b += 256) {
    const float4* p = (const float4*)(partial_sumw + (size_t)b * NHEAD);
    float4 a0 = p[0], a1 = p[1];
    sw[0] += a0.x; sw[1] += a0.y; sw[2] += a0.z; sw[3] += a0.w;
    sw[4] += a1.x; sw[5] += a1.y; sw[6] += a1.z; sw[7] += a1.w;
  }
#pragma unroll
  for (int m = 1; m < 64; m <<= 1) {
#pragma unroll
    for (int h = 0; h < NHEAD; ++h) sw[h] += __shfl_xor(sw[h], m, 64);
  }
  if (lane == 0) {
#pragma unroll
    for (int h = 0; h < NHEAD; ++h) swst[wave][h] = sw[h];
  }
  __syncthreads();
  if (t < NHEAD) sumw_s[t] = swst[0][t] + swst[1][t] + swst[2][t] + swst[3][t];
  const int o = blockIdx.x * 32 + (t & 31);
  const int g = t >> 5;
  float a = 0.f;
  for (int b = g; b < nblk; b += 8) a += partial_z[(size_t)b * (NHEAD * E_DIM) + o];
  red[t] = a;
  __syncthreads();
  if (t < 32) {
    float s2 = 0.f;
#pragma unroll
    for (int gg = 0; gg < 8; ++gg) s2 += red[gg * 32 + t];
    const int oo = blockIdx.x * 32 + t;
    zn[oo] = s2 / sumw_s[oo >> 10];
  }
}

__global__ __launch_bounds__(256) void proj_v(
    const float* __restrict__ W, const float* __restrict__ bias,
    const float* __restrict__ zn, float* __restrict__ attn)
{
  const int t = threadIdx.x, wave = t >> 6, lane = t & 63;
  const int o = blockIdx.x * 4 + wave;
  const float4* Wr = (const float4*)(W + ((size_t)2 * E_DIM + o) * E_DIM);
  const float4* zr = (const float4*)(zn + (size_t)(o >> 7) * E_DIM);
  float a = 0.f;
#pragma unroll
  for (int k = 0; k < 4; ++k) {
    float4 wv = Wr[lane + 64 * k];
    float4 zv = zr[lane + 64 * k];
    a += wv.x * zv.x + wv.y * zv.y + wv.z * zv.z + wv.w * zv.w;
  }
#pragma unroll
  for (int m = 1; m < 64; m <<= 1) a += __shfl_xor(a, m, 64);
  if (lane == 0) attn[o] = a + bias[2 * E_DIM + o];
}

__global__ __launch_bounds__(256) void proj_o(
    const float* __restrict__ Wo, const float* __restrict__ bo,
    const float* __restrict__ attn, float* __restrict__ out)
{
  const int t = threadIdx.x, wave = t >> 6, lane = t & 63;
  const int o = blockIdx.x * 4 + wave;
  const float4* Wr = (const float4*)(Wo + (size_t)o * E_DIM);
  const float4* vr = (const float4*)attn;
  float a = 0.f;
#pragma unroll
  for (int k = 0; k < 4; ++k) {
    float4 wv = Wr[lane + 64 * k];
    float4 vv = vr[lane + 64 * k];
    a += wv.x * vv.x + wv.y * vv.y + wv.z * vv.z + wv.w * vv.w;
  }
#pragma unroll
  for (int m = 1; m < 64; m <<= 1) a += __shfl_xor(a, m, 64);
  if (lane == 0) out[o] = a + bo[o];
}

extern "C" void kernel_launch(void* const* d_in, const int* in_sizes, int n_in,
                              void* d_out, int out_size, void* d_ws, size_t ws_size,
                              hipStream_t stream)
{
  const float* x  = (const float*)d_in[0];   // [32768,1024]
  const float* Wi = (const float*)d_in[1];   // [3072,1024]
  const float* bi = (const float*)d_in[2];   // [3072]
  const float* Wo = (const float*)d_in[3];   // [1024,1024]
  const float* bo = (const float*)d_in[4];   // [1024]
  float* out = (float*)d_out;                // [1024] fp32

  // workspace layout (bytes)
  char* ws = (char*)d_ws;
  float* q     = (float*)(ws + 0);           // 1024 f (fallback only)
  float* P_T   = (float*)(ws + 4096);        // 8192 f
  float* zn    = (float*)(ws + 36864);       // 8192 f
  float* attn  = (float*)(ws + 69632);       // 1024 f
  float* psumw = (float*)(ws + 73728);       // nblk*8 f
  int*   bar   = (int*)  (ws + 81920);       // barrier lines (2 KB)
  const size_t pz_off = 90112;
  float* pz    = (float*)(ws + pz_off);      // nblk*8192 f

  const size_t need_coop = pz_off + (size_t)NBLK * NHEAD * E_DIM * 4;
  if (ws_size >= need_coop) {
    hipMemsetAsync(bar, 0, 2048, stream);    // zero barrier lines
    mha_all<<<NBLK, 512, 0, stream>>>(x, Wi, bi, Wo, bo, out,
                                      P_T, zn, attn, psumw, pz, bar);
    return;
  }

  // fallback (small workspace): 6-dispatch pipeline
  int nblk = 128;
  if (ws_size >= pz_off + (size_t)512 * NHEAD * E_DIM * 4) nblk = 512;
  else if (ws_size >= pz_off + (size_t)256 * NHEAD * E_DIM * 4) nblk = 256;
  const int rows_per_blk = L_SEQ / nblk;

  proj_q     <<<256, 256, 0, stream>>>(Wi, bi, x, q);
  make_p     <<<dim3(8, 8), 128, 0, stream>>>(Wi, q, P_T);
  attn_fused5<<<nblk, 512, 0, stream>>>(x, P_T, pz, psumw, rows_per_blk);
  reduce_z   <<<256, 256, 0, stream>>>(pz, psumw, zn, nblk);
  proj_v     <<<256, 256, 0, stream>>>(Wi, bi, zn, attn);
  proj_o     <<<256, 256, 0, stream>>>(Wo, bo, attn, out);
}

// Round 6
// 286.161 us; speedup vs baseline: 1.2265x; 1.0480x over previous
//
#include <hip/hip_runtime.h>
#include <math.h>

// Single-query MHA, algebraically collapsed:
//   s[l,h] = x_l . p_h   (p_h = Wk_h^T q_h / sqrt(D); k-bias shift cancels in softmax)
//   z_h    = sum_l softmax(s)_lh * x_l ;  attn = Wv z + bv ; out = Wo attn + bo
//
// v10: ALL stages grid-wide. v9 post-mortem: barrier mechanics fixed but
// S1+S2 ran on 8 blocks (1MB cold weights each, latency-bound ~40GB/s/CU)
// = ~20-25us serial on 3% of the machine, plus idle-half grids in S5/S6.
// v10 stage A: block (h=bid>>5, ec=bid&31) redundantly computes q_h (Wq
// panel L2-shared by 32 blocks) then one 32-col chunk of P_T -> one less
// barrier (4 total), no narrow stage anywhere. S3 waves stream contiguous
// 32-row strips. S5/S6 use all 256 blocks (4 waves each).

#define L_SEQ   32768
#define E_DIM   1024
#define NHEAD   8
#define HDIM    128
#define NBLK    256          // one block per CU; co-residency by construction

// direct HBM->LDS (fallback path only)
#define GLD16(gp, lp)                                                   \
  __builtin_amdgcn_global_load_lds(                                     \
      (const __attribute__((address_space(1))) void*)(gp),              \
      (__attribute__((address_space(3))) void*)(lp), 16, 0, 0)

// ---- grid barrier: relaxed hierarchical arrivals, relaxed poll, 2 fences ----
// bar int offsets: [i*32] i=0..7 arrival lines; [256] level-2; [320] release.
// Zeroed host-side before launch.
__device__ __forceinline__ void gbar(int* bar, int phase)
{
  __syncthreads();
  if (threadIdx.x == 0) {
    __threadfence();                                   // release our writes
    int* cnt  = bar + ((blockIdx.x & 7) << 5);
    int* lvl2 = bar + 256;
    int* rel  = bar + 320;
    bool last = false;
    if (__hip_atomic_fetch_add(cnt, 1, __ATOMIC_RELAXED,
                               __HIP_MEMORY_SCOPE_AGENT) == 31) {
      if (__hip_atomic_fetch_add(lvl2, 1, __ATOMIC_RELAXED,
                                 __HIP_MEMORY_SCOPE_AGENT) == 7) {
        __threadfence();
#pragma unroll
        for (int i = 0; i < 8; ++i)
          __hip_atomic_store(bar + (i << 5), 0, __ATOMIC_RELAXED,
                             __HIP_MEMORY_SCOPE_AGENT);
        __hip_atomic_store(lvl2, 0, __ATOMIC_RELAXED, __HIP_MEMORY_SCOPE_AGENT);
        __hip_atomic_store(rel, phase, __ATOMIC_RELEASE,
                           __HIP_MEMORY_SCOPE_AGENT);
        last = true;
      }
    }
    if (!last) {
      while (__hip_atomic_load(rel, __ATOMIC_RELAXED,
                               __HIP_MEMORY_SCOPE_AGENT) < phase)
        __builtin_amdgcn_s_sleep(1);
    }
    __threadfence();                                   // invalidate stale caches
  }
  __syncthreads();
}

__global__ __launch_bounds__(512, 1) void mha_all(
    const float* __restrict__ x,   const float* __restrict__ Wi,
    const float* __restrict__ bi,  const float* __restrict__ Wo,
    const float* __restrict__ bo,  float* __restrict__ out,
    float* __restrict__ P_T, float* __restrict__ zn,
    float* __restrict__ attn, float* __restrict__ psumw,
    float* __restrict__ pz, int* bar)
{
  __shared__ __align__(16) float smem[8 * 4 * E_DIM];   // 128 KB, reused per stage
  __shared__ __align__(16) float swq[32];
  __shared__ __align__(16) float swst4[8][NHEAD];
  __shared__ float sumw_s[NHEAD];

  const int t    = threadIdx.x;
  const int wave = t >> 6;
  const int lane = t & 63;
  const int bid  = blockIdx.x;

  // ------- Stage A (ALL blocks): redundant q_h, then P_T[h][ec*32..+32) -------
  {
    const int h  = bid >> 5;                           // head
    const int ec = bid & 31;                           // 32-col chunk
    float* q_lds = smem;                               // 128 floats
    float (*ps)[32] = (float(*)[32])(smem + 256);      // [16][32]

    // q_h[d] = Wq[h*128+d] . x0 + bq : 4 threads per d, 256 elems each
    {
      const int d   = t >> 2;                          // 0..127
      const int sub = t & 3;
      const float4* W4 = (const float4*)(Wi + (size_t)(h * HDIM + d) * E_DIM + sub * 256);
      const float4* X4 = (const float4*)(x + sub * 256);
      float a = 0.f;
#pragma unroll 8
      for (int j = 0; j < 64; ++j) {
        const float4 wv = W4[j], xv = X4[j];
        a += wv.x * xv.x + wv.y * xv.y + wv.z * xv.z + wv.w * xv.w;
      }
      a += __shfl_xor(a, 1, 64);
      a += __shfl_xor(a, 2, 64);
      if (sub == 0) q_lds[d] = a + bi[h * HDIM + d];
    }
    __syncthreads();

    // P chunk: col = ec*32 + (t&31); partial over 8 d's per group dg = t>>5
    {
      const int dg  = t >> 5;                          // 0..15
      const int cl  = t & 31;
      const int col = ec * 32 + cl;
      const float* Wk = Wi + ((size_t)E_DIM + h * HDIM + dg * 8) * E_DIM + col;
      float a = 0.f;
#pragma unroll
      for (int i = 0; i < 8; ++i)
        a += q_lds[dg * 8 + i] * Wk[(size_t)i * E_DIM];
      ps[dg][cl] = a;
    }
    __syncthreads();
    if (t < 32) {
      float s = 0.f;
#pragma unroll
      for (int g = 0; g < 16; ++g) s += ps[g][t];
      P_T[(size_t)h * E_DIM + ec * 32 + t] = s * 0.08838834764831845f;  // 1/sqrt(128)
    }
    __syncthreads();                                   // smem reused in S3
  }
  gbar(bar, 1);

  // ------- S3: scores + softmax-weights + weighted-x (all blocks) -------
  {
    const int hq   = wave & 1;                         // head quad: 4*hq..4*hq+3
    const int rgrp = wave >> 1;                        // 0..3
    const size_t row0 = (size_t)bid * 128 + (size_t)rgrp * 32;  // contiguous strip

    float4 p[4][4];                                    // 4 heads x 16 cols/lane
#pragma unroll
    for (int j = 0; j < 4; ++j) {
      const float4* P0 = (const float4*)(P_T + (size_t)(4 * hq + j) * E_DIM);
#pragma unroll
      for (int c = 0; c < 4; ++c) p[j][c] = P0[64 * c + lane];
    }

    float4 z[4][4];
#pragma unroll
    for (int j = 0; j < 4; ++j)
#pragma unroll
      for (int c = 0; c < 4; ++c) z[j][c] = make_float4(0.f, 0.f, 0.f, 0.f);
    float sumw[4] = {0.f, 0.f, 0.f, 0.f};

    float4 xa[4], xb[4];
    {
      const float4* g0 = (const float4*)(x + row0 * E_DIM);
      const float4* g1 = (const float4*)(x + (row0 + 1) * E_DIM);
#pragma unroll
      for (int c = 0; c < 4; ++c) { xa[c] = g0[64 * c + lane]; xb[c] = g1[64 * c + lane]; }
    }

#pragma unroll 2
    for (int k = 0; k < 32; ++k) {
      float4 xn[4];
      if (k < 30) {
        const float4* g = (const float4*)(x + (row0 + k + 2) * E_DIM);
#pragma unroll
        for (int c = 0; c < 4; ++c) xn[c] = g[64 * c + lane];
      }

      float s[4] = {0.f, 0.f, 0.f, 0.f};
#pragma unroll
      for (int j = 0; j < 4; ++j)
#pragma unroll
        for (int c = 0; c < 4; ++c)
          s[j] += xa[c].x * p[j][c].x + xa[c].y * p[j][c].y +
                  xa[c].z * p[j][c].z + xa[c].w * p[j][c].w;

#pragma unroll
      for (int m = 1; m < 64; m <<= 1) {
#pragma unroll
        for (int j = 0; j < 4; ++j) s[j] += __shfl_xor(s[j], m, 64);
      }

      float w[4];
#pragma unroll
      for (int j = 0; j < 4; ++j) { w[j] = __expf(s[j]); sumw[j] += w[j]; }

#pragma unroll
      for (int j = 0; j < 4; ++j)
#pragma unroll
        for (int c = 0; c < 4; ++c) {
          z[j][c].x += w[j] * xa[c].x; z[j][c].y += w[j] * xa[c].y;
          z[j][c].z += w[j] * xa[c].z; z[j][c].w += w[j] * xa[c].w;
        }

#pragma unroll
      for (int c = 0; c < 4; ++c) { xa[c] = xb[c]; xb[c] = xn[c]; }
    }

    // epilogue: stage wave partials in LDS, combine, write pz
    {
      float4* zd = (float4*)(smem + wave * 4096);
#pragma unroll
      for (int j = 0; j < 4; ++j)
#pragma unroll
        for (int c = 0; c < 4; ++c) zd[j * 256 + 64 * c + lane] = z[j][c];
      if (lane == 0) {
#pragma unroll
        for (int j = 0; j < 4; ++j) swq[wave * 4 + j] = sumw[j];
      }
    }
    __syncthreads();
    {
      float* pzb = pz + (size_t)bid * (NHEAD * E_DIM);
#pragma unroll
      for (int m = 0; m < 16; ++m) {
        const int idx = t + 512 * m;                   // 0..8191 = h*1024+e
        const int h  = idx >> 10;
        const int e  = idx & 1023;
        const int hh = h >> 2;                         // hq
        const int j  = h & 3;
        float v = 0.f;
#pragma unroll
        for (int rg2 = 0; rg2 < 4; ++rg2)
          v += smem[(2 * rg2 + hh) * 4096 + j * 1024 + e];
        pzb[idx] = v;
      }
    }
    if (t < NHEAD) {
      const int hh = t >> 2, j = t & 3;
      float s2 = 0.f;
#pragma unroll
      for (int rg2 = 0; rg2 < 4; ++rg2) s2 += swq[(2 * rg2 + hh) * 4 + j];
      psumw[bid * NHEAD + t] = s2;
    }
  }
  gbar(bar, 2);

  // ------- S4: zn[h][e] = sum_b pz / sum_b psumw (all blocks) -------
  {
    float* red = smem;                                 // 512 floats
    float sw[NHEAD];
#pragma unroll
    for (int h = 0; h < NHEAD; ++h) sw[h] = 0.f;
    for (int b2 = t; b2 < NBLK; b2 += 512) {
      const float4* p = (const float4*)(psumw + (size_t)b2 * NHEAD);
      float4 a0 = p[0], a1 = p[1];
      sw[0] += a0.x; sw[1] += a0.y; sw[2] += a0.z; sw[3] += a0.w;
      sw[4] += a1.x; sw[5] += a1.y; sw[6] += a1.z; sw[7] += a1.w;
    }
#pragma unroll
    for (int m = 1; m < 64; m <<= 1) {
#pragma unroll
      for (int h = 0; h < NHEAD; ++h) sw[h] += __shfl_xor(sw[h], m, 64);
    }
    if (lane == 0) {
#pragma unroll
      for (int h = 0; h < NHEAD; ++h) swst4[wave][h] = sw[h];
    }
    __syncthreads();
    if (t < NHEAD) {
      float s = 0.f;
#pragma unroll
      for (int wv = 0; wv < 8; ++wv) s += swst4[wv][t];
      sumw_s[t] = s;
    }

    const int o = bid * 32 + (t & 31);
    const int g = t >> 5;                              // 16 column-groups
    float a = 0.f;
    for (int b2 = g; b2 < NBLK; b2 += 16) a += pz[(size_t)b2 * (NHEAD * E_DIM) + o];
    red[t] = a;
    __syncthreads();
    if (t < 32) {
      float s2 = 0.f;
#pragma unroll
      for (int gg = 0; gg < 16; ++gg) s2 += red[gg * 32 + t];
      const int oo = bid * 32 + t;
      zn[oo] = s2 / sumw_s[oo >> 10];                  // oo = h*1024 + e
    }
  }
  gbar(bar, 3);

  // ------- S5: attn[o] = Wv[o] . zn[h(o)] + bv[o] (all blocks, 4 waves) -------
  if (wave < 4) {
    const int o = bid * 4 + wave;
    const float4* Wr = (const float4*)(Wi + ((size_t)2 * E_DIM + o) * E_DIM);
    const float4* zr = (const float4*)(zn + (size_t)(o >> 7) * E_DIM);
    float a = 0.f;
#pragma unroll
    for (int k = 0; k < 4; ++k) {
      float4 wv = Wr[lane + 64 * k];
      float4 zv = zr[lane + 64 * k];
      a += wv.x * zv.x + wv.y * zv.y + wv.z * zv.z + wv.w * zv.w;
    }
#pragma unroll
    for (int m = 1; m < 64; m <<= 1) a += __shfl_xor(a, m, 64);
    if (lane == 0) attn[o] = a + bi[2 * E_DIM + o];
  }
  gbar(bar, 4);

  // ------- S6: out[e] = Wo[e] . attn + bo[e] (all blocks, 4 waves) -------
  if (wave < 4) {
    const int o = bid * 4 + wave;
    const float4* Wr = (const float4*)(Wo + (size_t)o * E_DIM);
    const float4* vr = (const float4*)attn;
    float a = 0.f;
#pragma unroll
    for (int k = 0; k < 4; ++k) {
      float4 wv = Wr[lane + 64 * k];
      float4 vv = vr[lane + 64 * k];
      a += wv.x * vv.x + wv.y * vv.y + wv.z * vv.z + wv.w * vv.w;
    }
#pragma unroll
    for (int m = 1; m < 64; m <<= 1) a += __shfl_xor(a, m, 64);
    if (lane == 0) out[o] = a + bo[o];
  }
}

// ================= fallback multi-kernel path (used only if ws too small) =================

__global__ __launch_bounds__(256) void proj_q(
    const float* __restrict__ W, const float* __restrict__ bias,
    const float* __restrict__ x, float* __restrict__ q)
{
  const int t = threadIdx.x, wave = t >> 6, lane = t & 63;
  const int o = blockIdx.x * 4 + wave;
  const float4* Wr = (const float4*)(W + (size_t)o * E_DIM);
  const float4* xr = (const float4*)x;
  float a = 0.f;
#pragma unroll
  for (int k = 0; k < 4; ++k) {
    float4 wv = Wr[lane + 64 * k];
    float4 xv = xr[lane + 64 * k];
    a += wv.x * xv.x + wv.y * xv.y + wv.z * xv.z + wv.w * xv.w;
  }
#pragma unroll
  for (int m = 1; m < 64; m <<= 1) a += __shfl_xor(a, m, 64);
  if (lane == 0) q[o] = a + bias[o];
}

__global__ __launch_bounds__(128) void make_p(
    const float* __restrict__ W, const float* __restrict__ q,
    float* __restrict__ P_T)
{
  const int h = blockIdx.y;
  const int e = blockIdx.x * 128 + threadIdx.x;
  const float* qh = q + h * HDIM;
  const float* Wb = W + ((size_t)E_DIM + (size_t)h * HDIM) * E_DIM + e;
  float a0 = 0.f, a1 = 0.f, a2 = 0.f, a3 = 0.f;
#pragma unroll 4
  for (int d = 0; d < HDIM; d += 4) {
    a0 += qh[d + 0] * Wb[(size_t)(d + 0) * E_DIM];
    a1 += qh[d + 1] * Wb[(size_t)(d + 1) * E_DIM];
    a2 += qh[d + 2] * Wb[(size_t)(d + 2) * E_DIM];
    a3 += qh[d + 3] * Wb[(size_t)(d + 3) * E_DIM];
  }
  P_T[h * E_DIM + e] = ((a0 + a1) + (a2 + a3)) * 0.08838834764831845f;
}

__global__ __launch_bounds__(512, 2) void attn_fused5(
    const float* __restrict__ x, const float* __restrict__ P_T,
    float* __restrict__ partial_z, float* __restrict__ partial_sumw,
    int rows_per_blk)
{
  __shared__ __align__(16) float sbuf[2][8][E_DIM];
  __shared__ float swst[16];
  const int t = threadIdx.x, wave = t >> 6, lane = t & 63;
  const int rh = wave >> 2, h0 = (wave & 3) * 2;
  const size_t row0 = (size_t)blockIdx.x * rows_per_blk;
  const int ntiles = rows_per_blk / 8;

  float4 p0[4], p1[4];
  {
    const float4* P0 = (const float4*)(P_T + (size_t)h0 * E_DIM);
    const float4* P1 = (const float4*)(P_T + (size_t)(h0 + 1) * E_DIM);
#pragma unroll
    for (int k = 0; k < 4; ++k) { p0[k] = P0[64 * k + lane]; p1[k] = P1[64 * k + lane]; }
  }
  float4 z0[4], z1[4];
#pragma unroll
  for (int k = 0; k < 4; ++k) {
    z0[k] = make_float4(0.f, 0.f, 0.f, 0.f);
    z1[k] = make_float4(0.f, 0.f, 0.f, 0.f);
  }
  float sumw0 = 0.f, sumw1 = 0.f;
  {
    const float* g = x + (row0 + wave) * E_DIM + 4 * lane;
#pragma unroll
    for (int k = 0; k < 4; ++k) GLD16(g + k * 256, &sbuf[0][wave][k * 256]);
  }
  __syncthreads();
  for (int tile = 0; tile < ntiles; ++tile) {
    const int buf = tile & 1;
    if (tile + 1 < ntiles) {
      const float* g = x + (row0 + (size_t)(tile + 1) * 8 + wave) * E_DIM + 4 * lane;
#pragma unroll
      for (int k = 0; k < 4; ++k) GLD16(g + k * 256, &sbuf[buf ^ 1][wave][k * 256]);
    }
#pragma unroll
    for (int rl = 0; rl < 4; ++rl) {
      const float4* xr4 = (const float4*)&sbuf[buf][rh * 4 + rl][0];
      float4 xr[4];
#pragma unroll
      for (int k = 0; k < 4; ++k) xr[k] = xr4[64 * k + lane];
      float s0 = 0.f, s1 = 0.f;
#pragma unroll
      for (int k = 0; k < 4; ++k) {
        s0 += xr[k].x * p0[k].x + xr[k].y * p0[k].y + xr[k].z * p0[k].z + xr[k].w * p0[k].w;
        s1 += xr[k].x * p1[k].x + xr[k].y * p1[k].y + xr[k].z * p1[k].z + xr[k].w * p1[k].w;
      }
      const bool odd = (lane & 1);
      float keep = odd ? s1 : s0;
      float oth  = odd ? s0 : s1;
      float ts = keep + __shfl_xor(oth, 1, 64);
      ts += __shfl_xor(ts, 2, 64);
      ts += __shfl_xor(ts, 4, 64);
      ts += __shfl_xor(ts, 8, 64);
      ts += __shfl_xor(ts, 16, 64);
      ts += __shfl_xor(ts, 32, 64);
      const float ex = __expf(ts);
      const float ox = __shfl_xor(ex, 1, 64);
      const float w0 = odd ? ox : ex;
      const float w1 = odd ? ex : ox;
      sumw0 += w0; sumw1 += w1;
#pragma unroll
      for (int k = 0; k < 4; ++k) {
        z0[k].x += w0 * xr[k].x; z0[k].y += w0 * xr[k].y;
        z0[k].z += w0 * xr[k].z; z0[k].w += w0 * xr[k].w;
        z1[k].x += w1 * xr[k].x; z1[k].y += w1 * xr[k].y;
        z1[k].z += w1 * xr[k].z; z1[k].w += w1 * xr[k].w;
      }
    }
    __syncthreads();
  }
  float (*zs)[E_DIM] = (float(*)[E_DIM])&sbuf[0][0][0];
  {
    float4* zd0 = (float4*)&zs[2 * wave][0];
    float4* zd1 = (float4*)&zs[2 * wave + 1][0];
#pragma unroll
    for (int k = 0; k < 4; ++k) { zd0[64 * k + lane] = z0[k]; zd1[64 * k + lane] = z1[k]; }
  }
  if (lane == 0) { swst[2 * wave] = sumw0; swst[2 * wave + 1] = sumw1; }
  __syncthreads();
  {
    const float4* zsv = (const float4*)&zs[0][0];
    float4* pzb = (float4*)(partial_z + (size_t)blockIdx.x * (NHEAD * E_DIM));
#pragma unroll
    for (int j = 0; j < 4; ++j) {
      const int idx = t + 512 * j;
      const float4 a = zsv[idx], b = zsv[idx + 2048];
      pzb[idx] = make_float4(a.x + b.x, a.y + b.y, a.z + b.z, a.w + b.w);
    }
  }
  if (t < NHEAD)
    partial_sumw[blockIdx.x * NHEAD + t] = swst[t] + swst[t + 8];
}

__global__ __launch_bounds__(256) void reduce_z(
    const float* __restrict__ partial_z, const float* __restrict__ partial_sumw,
    float* __restrict__ zn, int nblk)
{
  __shared__ float red[256];
  __shared__ __align__(16) float swst[4][NHEAD];
  __shared__ float sumw_s[NHEAD];
  const int t = threadIdx.x;
  const int lane = t & 63, wave = t >> 6;
  float sw[NHEAD];
#pragma unroll
  for (int h = 0; h < NHEAD; ++h) sw[h] = 0.f;
  for (int b = t; b < nblk; b += 256) {
    const float4* p = (const float4*)(partial_sumw + (size_t)b * NHEAD);
    float4 a0 = p[0], a1 = p[1];
    sw[0] += a0.x; sw[1] += a0.y; sw[2] += a0.z; sw[3] += a0.w;
    sw[4] += a1.x; sw[5] += a1.y; sw[6] += a1.z; sw[7] += a1.w;
  }
#pragma unroll
  for (int m = 1; m < 64; m <<= 1) {
#pragma unroll
    for (int h = 0; h < NHEAD; ++h) sw[h] += __shfl_xor(sw[h], m, 64);
  }
  if (lane == 0) {
#pragma unroll
    for (int h = 0; h < NHEAD; ++h) swst[wave][h] = sw[h];
  }
  __syncthreads();
  if (t < NHEAD) sumw_s[t] = swst[0][t] + swst[1][t] + swst[2][t] + swst[3][t];
  const int o = blockIdx.x * 32 + (t & 31);
  const int g = t >> 5;
  float a = 0.f;
  for (int b = g; b < nblk; b += 8) a += partial_z[(size_t)b * (NHEAD * E_DIM) + o];
  red[t] = a;
  __syncthreads();
  if (t < 32) {
    float s2 = 0.f;
#pragma unroll
    for (int gg = 0; gg < 8; ++gg) s2 += red[gg * 32 + t];
    const int oo = blockIdx.x * 32 + t;
    zn[oo] = s2 / sumw_s[oo >> 10];
  }
}

__global__ __launch_bounds__(256) void proj_v(
    const float* __restrict__ W, const float* __restrict__ bias,
    const float* __restrict__ zn, float* __restrict__ attn)
{
  const int t = threadIdx.x, wave = t >> 6, lane = t & 63;
  const int o = blockIdx.x * 4 + wave;
  const float4* Wr = (const float4*)(W + ((size_t)2 * E_DIM + o) * E_DIM);
  const float4* zr = (const float4*)(zn + (size_t)(o >> 7) * E_DIM);
  float a = 0.f;
#pragma unroll
  for (int k = 0; k < 4; ++k) {
    float4 wv = Wr[lane + 64 * k];
    float4 zv = zr[lane + 64 * k];
    a += wv.x * zv.x + wv.y * zv.y + wv.z * zv.z + wv.w * zv.w;
  }
#pragma unroll
  for (int m = 1; m < 64; m <<= 1) a += __shfl_xor(a, m, 64);
  if (lane == 0) attn[o] = a + bias[2 * E_DIM + o];
}

__global__ __launch_bounds__(256) void proj_o(
    const float* __restrict__ Wo, const float* __restrict__ bo,
    const float* __restrict__ attn, float* __restrict__ out)
{
  const int t = threadIdx.x, wave = t >> 6, lane = t & 63;
  const int o = blockIdx.x * 4 + wave;
  const float4* Wr = (const float4*)(Wo + (size_t)o * E_DIM);
  const float4* vr = (const float4*)attn;
  float a = 0.f;
#pragma unroll
  for (int k = 0; k < 4; ++k) {
    float4 wv = Wr[lane + 64 * k];
    float4 vv = vr[lane + 64 * k];
    a += wv.x * vv.x + wv.y * vv.y + wv.z * vv.z + wv.w * vv.w;
  }
#pragma unroll
  for (int m = 1; m < 64; m <<= 1) a += __shfl_xor(a, m, 64);
  if (lane == 0) out[o] = a + bo[o];
}

extern "C" void kernel_launch(void* const* d_in, const int* in_sizes, int n_in,
                              void* d_out, int out_size, void* d_ws, size_t ws_size,
                              hipStream_t stream)
{
  const float* x  = (const float*)d_in[0];   // [32768,1024]
  const float* Wi = (const float*)d_in[1];   // [3072,1024]
  const float* bi = (const float*)d_in[2];   // [3072]
  const float* Wo = (const float*)d_in[3];   // [1024,1024]
  const float* bo = (const float*)d_in[4];   // [1024]
  float* out = (float*)d_out;                // [1024] fp32

  // workspace layout (bytes)
  char* ws = (char*)d_ws;
  float* q     = (float*)(ws + 0);           // 1024 f (fallback only)
  float* P_T   = (float*)(ws + 4096);        // 8192 f
  float* zn    = (float*)(ws + 36864);       // 8192 f
  float* attn  = (float*)(ws + 69632);       // 1024 f
  float* psumw = (float*)(ws + 73728);       // nblk*8 f
  int*   bar   = (int*)  (ws + 81920);       // barrier lines (2 KB)
  const size_t pz_off = 90112;
  float* pz    = (float*)(ws + pz_off);      // nblk*8192 f

  const size_t need_coop = pz_off + (size_t)NBLK * NHEAD * E_DIM * 4;
  if (ws_size >= need_coop) {
    hipMemsetAsync(bar, 0, 2048, stream);    // zero barrier lines
    mha_all<<<NBLK, 512, 0, stream>>>(x, Wi, bi, Wo, bo, out,
                                      P_T, zn, attn, psumw, pz, bar);
    return;
  }

  // fallback (small workspace): 6-dispatch pipeline
  int nblk = 128;
  if (ws_size >= pz_off + (size_t)512 * NHEAD * E_DIM * 4) nblk = 512;
  else if (ws_size >= pz_off + (size_t)256 * NHEAD * E_DIM * 4) nblk = 256;
  const int rows_per_blk = L_SEQ / nblk;

  proj_q     <<<256, 256, 0, stream>>>(Wi, bi, x, q);
  make_p     <<<dim3(8, 8), 128, 0, stream>>>(Wi, q, P_T);
  attn_fused5<<<nblk, 512, 0, stream>>>(x, P_T, pz, psumw, rows_per_blk);
  reduce_z   <<<256, 256, 0, stream>>>(pz, psumw, zn, nblk);
  proj_v     <<<256, 256, 0, stream>>>(Wi, bi, zn, attn);
  proj_o     <<<256, 256, 0, stream>>>(Wo, bo, attn, out);
}

// Round 7
// 267.297 us; speedup vs baseline: 1.3130x; 1.0706x over previous
//
#include <hip/hip_runtime.h>
#include <math.h>

// Single-query MHA, algebraically collapsed:
//   s[l,h] = x_l . p_h   (p_h = Wk_h^T q_h / sqrt(D); k-bias shift cancels in softmax)
//   z_h    = sum_l softmax(s)_lh * x_l ;  attn = Wv z + bv ; out = Wo attn + bo
//
// v11: back to multi-dispatch, 5 kernels (v6 had 6), ALL verified components.
// Fused-single-dispatch experiments (v7-v10) concluded: software grid barrier
// (agent-scope fences = L2 wb/inv x 8 XCDs) + forced 1 block/CU occupancy cost
// MORE than the dispatch gaps they save (fused kernel alone 143-206us vs
// v6 kernel-sum ~100us). Dispatch boundaries do coherence in the CP for free.
//  k1 qp_fused  = v10 Stage A verbatim (redundant q_h per block, P_T chunk)
//  k2 attn_fused5 verbatim (v6-verified), nblk=512 -> 2 blocks/CU
//  k3 reduce_z, k4 proj_v, k5 proj_o verbatim.

#define L_SEQ   32768
#define E_DIM   1024
#define NHEAD   8
#define HDIM    128

// direct HBM->LDS, 16B per lane; gptr is PER-LANE, ldsptr is wave-uniform base
#define GLD16(gp, lp)                                                   \
  __builtin_amdgcn_global_load_lds(                                     \
      (const __attribute__((address_space(1))) void*)(gp),              \
      (__attribute__((address_space(3))) void*)(lp), 16, 0, 0)

// ---- k1: P_T[h][ec*32..+32) with block-local redundant q_h (v10 Stage A) ----
__global__ __launch_bounds__(512) void qp_fused(
    const float* __restrict__ x, const float* __restrict__ Wi,
    const float* __restrict__ bi, float* __restrict__ P_T)
{
  __shared__ __align__(16) float smem[256 + 16 * 32];   // q_lds[128(+pad)] + ps[16][32]
  const int t   = threadIdx.x;
  const int bid = blockIdx.x;
  const int h   = bid >> 5;                            // head
  const int ec  = bid & 31;                            // 32-col chunk
  float* q_lds = smem;                                 // 128 floats
  float (*ps)[32] = (float(*)[32])(smem + 256);        // [16][32]

  // q_h[d] = Wq[h*128+d] . x0 + bq : 4 threads per d, 256 elems each
  {
    const int d   = t >> 2;                            // 0..127
    const int sub = t & 3;
    const float4* W4 = (const float4*)(Wi + (size_t)(h * HDIM + d) * E_DIM + sub * 256);
    const float4* X4 = (const float4*)(x + sub * 256);
    float a = 0.f;
#pragma unroll 8
    for (int j = 0; j < 64; ++j) {
      const float4 wv = W4[j], xv = X4[j];
      a += wv.x * xv.x + wv.y * xv.y + wv.z * xv.z + wv.w * xv.w;
    }
    a += __shfl_xor(a, 1, 64);
    a += __shfl_xor(a, 2, 64);
    if (sub == 0) q_lds[d] = a + bi[h * HDIM + d];
  }
  __syncthreads();

  // P chunk: col = ec*32 + (t&31); partials over 8 d's per group dg = t>>5
  {
    const int dg  = t >> 5;                            // 0..15
    const int cl  = t & 31;
    const int col = ec * 32 + cl;
    const float* Wk = Wi + ((size_t)E_DIM + h * HDIM + dg * 8) * E_DIM + col;
    float a = 0.f;
#pragma unroll
    for (int i = 0; i < 8; ++i)
      a += q_lds[dg * 8 + i] * Wk[(size_t)i * E_DIM];
    ps[dg][cl] = a;
  }
  __syncthreads();
  if (t < 32) {
    float s = 0.f;
#pragma unroll
    for (int g = 0; g < 16; ++g) s += ps[g][t];
    P_T[(size_t)h * E_DIM + ec * 32 + t] = s * 0.08838834764831845f;   // 1/sqrt(128)
  }
}

// ---- k2: fused single-pass scores + softmax-weights + weighted-x (v6 verbatim) ----
__global__ __launch_bounds__(512, 2) void attn_fused5(
    const float* __restrict__ x, const float* __restrict__ P_T,
    float* __restrict__ partial_z, float* __restrict__ partial_sumw,
    int rows_per_blk)
{
  __shared__ __align__(16) float sbuf[2][8][E_DIM];
  __shared__ float swst[16];
  const int t = threadIdx.x, wave = t >> 6, lane = t & 63;
  const int rh = wave >> 2, h0 = (wave & 3) * 2;
  const size_t row0 = (size_t)blockIdx.x * rows_per_blk;
  const int ntiles = rows_per_blk / 8;

  float4 p0[4], p1[4];
  {
    const float4* P0 = (const float4*)(P_T + (size_t)h0 * E_DIM);
    const float4* P1 = (const float4*)(P_T + (size_t)(h0 + 1) * E_DIM);
#pragma unroll
    for (int k = 0; k < 4; ++k) { p0[k] = P0[64 * k + lane]; p1[k] = P1[64 * k + lane]; }
  }
  float4 z0[4], z1[4];
#pragma unroll
  for (int k = 0; k < 4; ++k) {
    z0[k] = make_float4(0.f, 0.f, 0.f, 0.f);
    z1[k] = make_float4(0.f, 0.f, 0.f, 0.f);
  }
  float sumw0 = 0.f, sumw1 = 0.f;
  {
    const float* g = x + (row0 + wave) * E_DIM + 4 * lane;
#pragma unroll
    for (int k = 0; k < 4; ++k) GLD16(g + k * 256, &sbuf[0][wave][k * 256]);
  }
  __syncthreads();
  for (int tile = 0; tile < ntiles; ++tile) {
    const int buf = tile & 1;
    if (tile + 1 < ntiles) {
      const float* g = x + (row0 + (size_t)(tile + 1) * 8 + wave) * E_DIM + 4 * lane;
#pragma unroll
      for (int k = 0; k < 4; ++k) GLD16(g + k * 256, &sbuf[buf ^ 1][wave][k * 256]);
    }
#pragma unroll
    for (int rl = 0; rl < 4; ++rl) {
      const float4* xr4 = (const float4*)&sbuf[buf][rh * 4 + rl][0];
      float4 xr[4];
#pragma unroll
      for (int k = 0; k < 4; ++k) xr[k] = xr4[64 * k + lane];
      float s0 = 0.f, s1 = 0.f;
#pragma unroll
      for (int k = 0; k < 4; ++k) {
        s0 += xr[k].x * p0[k].x + xr[k].y * p0[k].y + xr[k].z * p0[k].z + xr[k].w * p0[k].w;
        s1 += xr[k].x * p1[k].x + xr[k].y * p1[k].y + xr[k].z * p1[k].z + xr[k].w * p1[k].w;
      }
      const bool odd = (lane & 1);
      float keep = odd ? s1 : s0;
      float oth  = odd ? s0 : s1;
      float ts = keep + __shfl_xor(oth, 1, 64);
      ts += __shfl_xor(ts, 2, 64);
      ts += __shfl_xor(ts, 4, 64);
      ts += __shfl_xor(ts, 8, 64);
      ts += __shfl_xor(ts, 16, 64);
      ts += __shfl_xor(ts, 32, 64);
      const float ex = __expf(ts);
      const float ox = __shfl_xor(ex, 1, 64);
      const float w0 = odd ? ox : ex;
      const float w1 = odd ? ex : ox;
      sumw0 += w0; sumw1 += w1;
#pragma unroll
      for (int k = 0; k < 4; ++k) {
        z0[k].x += w0 * xr[k].x; z0[k].y += w0 * xr[k].y;
        z0[k].z += w0 * xr[k].z; z0[k].w += w0 * xr[k].w;
        z1[k].x += w1 * xr[k].x; z1[k].y += w1 * xr[k].y;
        z1[k].z += w1 * xr[k].z; z1[k].w += w1 * xr[k].w;
      }
    }
    __syncthreads();
  }
  float (*zs)[E_DIM] = (float(*)[E_DIM])&sbuf[0][0][0];
  {
    float4* zd0 = (float4*)&zs[2 * wave][0];
    float4* zd1 = (float4*)&zs[2 * wave + 1][0];
#pragma unroll
    for (int k = 0; k < 4; ++k) { zd0[64 * k + lane] = z0[k]; zd1[64 * k + lane] = z1[k]; }
  }
  if (lane == 0) { swst[2 * wave] = sumw0; swst[2 * wave + 1] = sumw1; }
  __syncthreads();
  {
    const float4* zsv = (const float4*)&zs[0][0];
    float4* pzb = (float4*)(partial_z + (size_t)blockIdx.x * (NHEAD * E_DIM));
#pragma unroll
    for (int j = 0; j < 4; ++j) {
      const int idx = t + 512 * j;
      const float4 a = zsv[idx], b = zsv[idx + 2048];
      pzb[idx] = make_float4(a.x + b.x, a.y + b.y, a.z + b.z, a.w + b.w);
    }
  }
  if (t < NHEAD)
    partial_sumw[blockIdx.x * NHEAD + t] = swst[t] + swst[t + 8];
}

// ---- k3: zn[h][e] = sum_b pz / sum_b psumw ----
__global__ __launch_bounds__(256) void reduce_z(
    const float* __restrict__ partial_z, const float* __restrict__ partial_sumw,
    float* __restrict__ zn, int nblk)
{
  __shared__ float red[256];
  __shared__ __align__(16) float swst[4][NHEAD];
  __shared__ float sumw_s[NHEAD];
  const int t = threadIdx.x;
  const int lane = t & 63, wave = t >> 6;
  float sw[NHEAD];
#pragma unroll
  for (int h = 0; h < NHEAD; ++h) sw[h] = 0.f;
  for (int b = t; b < nblk; b += 256) {
    const float4* p = (const float4*)(partial_sumw + (size_t)b * NHEAD);
    float4 a0 = p[0], a1 = p[1];
    sw[0] += a0.x; sw[1] += a0.y; sw[2] += a0.z; sw[3] += a0.w;
    sw[4] += a1.x; sw[5] += a1.y; sw[6] += a1.z; sw[7] += a1.w;
  }
#pragma unroll
  for (int m = 1; m < 64; m <<= 1) {
#pragma unroll
    for (int h = 0; h < NHEAD; ++h) sw[h] += __shfl_xor(sw[h], m, 64);
  }
  if (lane == 0) {
#pragma unroll
    for (int h = 0; h < NHEAD; ++h) swst[wave][h] = sw[h];
  }
  __syncthreads();
  if (t < NHEAD) sumw_s[t] = swst[0][t] + swst[1][t] + swst[2][t] + swst[3][t];
  const int o = blockIdx.x * 32 + (t & 31);
  const int g = t >> 5;
  float a = 0.f;
  for (int b = g; b < nblk; b += 8) a += partial_z[(size_t)b * (NHEAD * E_DIM) + o];
  red[t] = a;
  __syncthreads();
  if (t < 32) {
    float s2 = 0.f;
#pragma unroll
    for (int gg = 0; gg < 8; ++gg) s2 += red[gg * 32 + t];
    const int oo = blockIdx.x * 32 + t;
    zn[oo] = s2 / sumw_s[oo >> 10];
  }
}

// ---- k4: attn[o] = Wv[o] . zn[h(o)] + bv[o] ----
__global__ __launch_bounds__(256) void proj_v(
    const float* __restrict__ W, const float* __restrict__ bias,
    const float* __restrict__ zn, float* __restrict__ attn)
{
  const int t = threadIdx.x, wave = t >> 6, lane = t & 63;
  const int o = blockIdx.x * 4 + wave;
  const float4* Wr = (const float4*)(W + ((size_t)2 * E_DIM + o) * E_DIM);
  const float4* zr = (const float4*)(zn + (size_t)(o >> 7) * E_DIM);
  float a = 0.f;
#pragma unroll
  for (int k = 0; k < 4; ++k) {
    float4 wv = Wr[lane + 64 * k];
    float4 zv = zr[lane + 64 * k];
    a += wv.x * zv.x + wv.y * zv.y + wv.z * zv.z + wv.w * zv.w;
  }
#pragma unroll
  for (int m = 1; m < 64; m <<= 1) a += __shfl_xor(a, m, 64);
  if (lane == 0) attn[o] = a + bias[2 * E_DIM + o];
}

// ---- k5: out[e] = Wo[e] . attn + bo[e] ----
__global__ __launch_bounds__(256) void proj_o(
    const float* __restrict__ Wo, const float* __restrict__ bo,
    const float* __restrict__ attn, float* __restrict__ out)
{
  const int t = threadIdx.x, wave = t >> 6, lane = t & 63;
  const int o = blockIdx.x * 4 + wave;
  const float4* Wr = (const float4*)(Wo + (size_t)o * E_DIM);
  const float4* vr = (const float4*)attn;
  float a = 0.f;
#pragma unroll
  for (int k = 0; k < 4; ++k) {
    float4 wv = Wr[lane + 64 * k];
    float4 vv = vr[lane + 64 * k];
    a += wv.x * vv.x + wv.y * vv.y + wv.z * vv.z + wv.w * vv.w;
  }
#pragma unroll
  for (int m = 1; m < 64; m <<= 1) a += __shfl_xor(a, m, 64);
  if (lane == 0) out[o] = a + bo[o];
}

// ---- fallback front-end kernels (tiny-ws path keeps old proj_q/make_p) ----
__global__ __launch_bounds__(256) void proj_q(
    const float* __restrict__ W, const float* __restrict__ bias,
    const float* __restrict__ x, float* __restrict__ q)
{
  const int t = threadIdx.x, wave = t >> 6, lane = t & 63;
  const int o = blockIdx.x * 4 + wave;
  const float4* Wr = (const float4*)(W + (size_t)o * E_DIM);
  const float4* xr = (const float4*)x;
  float a = 0.f;
#pragma unroll
  for (int k = 0; k < 4; ++k) {
    float4 wv = Wr[lane + 64 * k];
    float4 xv = xr[lane + 64 * k];
    a += wv.x * xv.x + wv.y * xv.y + wv.z * xv.z + wv.w * xv.w;
  }
#pragma unroll
  for (int m = 1; m < 64; m <<= 1) a += __shfl_xor(a, m, 64);
  if (lane == 0) q[o] = a + bias[o];
}

__global__ __launch_bounds__(128) void make_p(
    const float* __restrict__ W, const float* __restrict__ q,
    float* __restrict__ P_T)
{
  const int h = blockIdx.y;
  const int e = blockIdx.x * 128 + threadIdx.x;
  const float* qh = q + h * HDIM;
  const float* Wb = W + ((size_t)E_DIM + (size_t)h * HDIM) * E_DIM + e;
  float a0 = 0.f, a1 = 0.f, a2 = 0.f, a3 = 0.f;
#pragma unroll 4
  for (int d = 0; d < HDIM; d += 4) {
    a0 += qh[d + 0] * Wb[(size_t)(d + 0) * E_DIM];
    a1 += qh[d + 1] * Wb[(size_t)(d + 1) * E_DIM];
    a2 += qh[d + 2] * Wb[(size_t)(d + 2) * E_DIM];
    a3 += qh[d + 3] * Wb[(size_t)(d + 3) * E_DIM];
  }
  P_T[h * E_DIM + e] = ((a0 + a1) + (a2 + a3)) * 0.08838834764831845f;
}

extern "C" void kernel_launch(void* const* d_in, const int* in_sizes, int n_in,
                              void* d_out, int out_size, void* d_ws, size_t ws_size,
                              hipStream_t stream)
{
  const float* x  = (const float*)d_in[0];   // [32768,1024]
  const float* Wi = (const float*)d_in[1];   // [3072,1024]
  const float* bi = (const float*)d_in[2];   // [3072]
  const float* Wo = (const float*)d_in[3];   // [1024,1024]
  const float* bo = (const float*)d_in[4];   // [1024]
  float* out = (float*)d_out;                // [1024] fp32

  // workspace layout (bytes)
  char* ws = (char*)d_ws;
  float* q     = (float*)(ws + 0);           // 1024 f (fallback only)
  float* P_T   = (float*)(ws + 4096);        // 8192 f
  float* zn    = (float*)(ws + 36864);       // 8192 f
  float* attn  = (float*)(ws + 69632);       // 1024 f
  float* psumw = (float*)(ws + 73728);       // nblk*8 f (512*8*4 = 16KB max)
  const size_t pz_off = 90112;
  float* pz    = (float*)(ws + pz_off);      // nblk*8192 f

  // pick partial-block count from available workspace (constant across calls)
  int nblk = 128;
  if (ws_size >= pz_off + (size_t)512 * NHEAD * E_DIM * 4) nblk = 512;
  else if (ws_size >= pz_off + (size_t)256 * NHEAD * E_DIM * 4) nblk = 256;
  const int rows_per_blk = L_SEQ / nblk;

  if (nblk == 512) {
    qp_fused <<<256, 512, 0, stream>>>(x, Wi, bi, P_T);
  } else {
    proj_q   <<<256, 256, 0, stream>>>(Wi, bi, x, q);
    make_p   <<<dim3(8, 8), 128, 0, stream>>>(Wi, q, P_T);
  }
  attn_fused5<<<nblk, 512, 0, stream>>>(x, P_T, pz, psumw, rows_per_blk);
  reduce_z   <<<256, 256, 0, stream>>>(pz, psumw, zn, nblk);
  proj_v     <<<256, 256, 0, stream>>>(Wi, bi, zn, attn);
  proj_o     <<<256, 256, 0, stream>>>(Wo, bo, attn, out);
}

// Round 8
// 242.523 us; speedup vs baseline: 1.4472x; 1.1022x over previous
//
#include <hip/hip_runtime.h>
#include <math.h>

// Single-query MHA, algebraically collapsed:
//   s[l,h] = x_l . p_h   (p_h = Wk_h^T q_h / sqrt(D); k-bias shift cancels in softmax)
//   z_h    = sum_l softmax(s)_lh * x_l ;  attn = Wv z + bv ; out = Wo attn + bo
//
// v12 = v6 (measured best, 241-242us) + ONE change: make_p -> make_p2.
// Session conclusions baked in:
//  - fused single-dispatch abandoned (v7-v10: grid-barrier coherence + 1 blk/CU
//    => fused kernel alone 143-206us > v6's whole kernel sum).
//  - qp_fused (redundant per-block q) abandoned (v11: +25us vs v6 front-end;
//    128MB aggregate redundant Wq traffic).
//  - make_p2: 256 blocks x 256 thr (vs 64 x 128), 8-way d-split -> 16
//    independent loads/thread (vs 128 chained), LDS combine. Same 4MB Wk
//    traffic, full CU occupancy, ~4-8x shorter latency chain.

#define L_SEQ   32768
#define E_DIM   1024
#define NHEAD   8
#define HDIM    128
#define TILE_R  8

// direct HBM->LDS, 16B per lane; gptr is PER-LANE, ldsptr is wave-uniform base
#define GLD16(gp, lp)                                                   \
  __builtin_amdgcn_global_load_lds(                                     \
      (const __attribute__((address_space(1))) void*)(gp),              \
      (__attribute__((address_space(3))) void*)(lp), 16, 0, 0)

// ---------------- q = Wq x0 + bq : wave-per-output GEMV ----------------
__global__ __launch_bounds__(256) void proj_q(
    const float* __restrict__ W, const float* __restrict__ bias,
    const float* __restrict__ x, float* __restrict__ q)
{
  const int t = threadIdx.x, wave = t >> 6, lane = t & 63;
  const int o = blockIdx.x * 4 + wave;
  const float4* Wr = (const float4*)(W + (size_t)o * E_DIM);
  const float4* xr = (const float4*)x;   // row 0 of x
  float a = 0.f;
#pragma unroll
  for (int k = 0; k < 4; ++k) {
    float4 wv = Wr[lane + 64 * k];
    float4 xv = xr[lane + 64 * k];
    a += wv.x * xv.x + wv.y * xv.y + wv.z * xv.z + wv.w * xv.w;
  }
#pragma unroll
  for (int m = 1; m < 64; m <<= 1) a += __shfl_xor(a, m, 64);
  if (lane == 0) q[o] = a + bias[o];
}

// ---- make_p2: P_T[h][e] = (1/sqrt(D)) sum_d q[h*128+d] * Wk[h*128+d][e] ----
// grid dim3(32,8) x 256 thr: block (h=by, ec=bx 32-col chunk);
// thread (dg = t>>5 owns 16 d's, cl = t&31): 16 INDEPENDENT strided loads,
// then 8-way LDS combine. Full-occupancy, short latency chain.
__global__ __launch_bounds__(256) void make_p2(
    const float* __restrict__ W, const float* __restrict__ q,
    float* __restrict__ P_T)
{
  __shared__ __align__(16) float ps[8][32];
  const int t  = threadIdx.x;
  const int h  = blockIdx.y;           // head
  const int ec = blockIdx.x;           // 32-col chunk
  const int cl = t & 31;
  const int dg = t >> 5;               // d-group of 16
  const float* Wb = W + ((size_t)E_DIM + h * HDIM + dg * 16) * E_DIM + ec * 32 + cl;
  const float* qh = q + h * HDIM + dg * 16;
  float a = 0.f;
#pragma unroll
  for (int i = 0; i < 16; ++i)
    a += qh[i] * Wb[(size_t)i * E_DIM];
  ps[dg][cl] = a;
  __syncthreads();
  if (t < 32) {
    float s = 0.f;
#pragma unroll
    for (int g = 0; g < 8; ++g) s += ps[g][t];
    P_T[(size_t)h * E_DIM + ec * 32 + t] = s * 0.08838834764831845f;   // 1/sqrt(128)
  }
}

// ---- fused single-pass scores + softmax-weights + weighted-x (v6 verbatim) ----
__global__ __launch_bounds__(512, 2) void attn_fused5(
    const float* __restrict__ x, const float* __restrict__ P_T,
    float* __restrict__ partial_z, float* __restrict__ partial_sumw,
    int rows_per_blk)
{
  __shared__ __align__(16) float sbuf[2][TILE_R][E_DIM];
  __shared__ float swst[16];
  const int t = threadIdx.x, wave = t >> 6, lane = t & 63;
  const int rh = wave >> 2, h0 = (wave & 3) * 2;
  const size_t row0 = (size_t)blockIdx.x * rows_per_blk;
  const int ntiles = rows_per_blk / TILE_R;

  float4 p0[4], p1[4];
  {
    const float4* P0 = (const float4*)(P_T + (size_t)h0 * E_DIM);
    const float4* P1 = (const float4*)(P_T + (size_t)(h0 + 1) * E_DIM);
#pragma unroll
    for (int k = 0; k < 4; ++k) { p0[k] = P0[64 * k + lane]; p1[k] = P1[64 * k + lane]; }
  }
  float4 z0[4], z1[4];
#pragma unroll
  for (int k = 0; k < 4; ++k) {
    z0[k] = make_float4(0.f, 0.f, 0.f, 0.f);
    z1[k] = make_float4(0.f, 0.f, 0.f, 0.f);
  }
  float sumw0 = 0.f, sumw1 = 0.f;
  {
    const float* g = x + (row0 + wave) * E_DIM + 4 * lane;
#pragma unroll
    for (int k = 0; k < 4; ++k) GLD16(g + k * 256, &sbuf[0][wave][k * 256]);
  }
  __syncthreads();
  for (int tile = 0; tile < ntiles; ++tile) {
    const int buf = tile & 1;
    if (tile + 1 < ntiles) {
      const float* g = x + (row0 + (size_t)(tile + 1) * TILE_R + wave) * E_DIM + 4 * lane;
#pragma unroll
      for (int k = 0; k < 4; ++k) GLD16(g + k * 256, &sbuf[buf ^ 1][wave][k * 256]);
    }
#pragma unroll
    for (int rl = 0; rl < 4; ++rl) {
      const float4* xr4 = (const float4*)&sbuf[buf][rh * 4 + rl][0];
      float4 xr[4];
#pragma unroll
      for (int k = 0; k < 4; ++k) xr[k] = xr4[64 * k + lane];
      float s0 = 0.f, s1 = 0.f;
#pragma unroll
      for (int k = 0; k < 4; ++k) {
        s0 += xr[k].x * p0[k].x + xr[k].y * p0[k].y + xr[k].z * p0[k].z + xr[k].w * p0[k].w;
        s1 += xr[k].x * p1[k].x + xr[k].y * p1[k].y + xr[k].z * p1[k].z + xr[k].w * p1[k].w;
      }
      const bool odd = (lane & 1);
      float keep = odd ? s1 : s0;
      float oth  = odd ? s0 : s1;
      float ts = keep + __shfl_xor(oth, 1, 64);
      ts += __shfl_xor(ts, 2, 64);
      ts += __shfl_xor(ts, 4, 64);
      ts += __shfl_xor(ts, 8, 64);
      ts += __shfl_xor(ts, 16, 64);
      ts += __shfl_xor(ts, 32, 64);
      const float ex = __expf(ts);
      const float ox = __shfl_xor(ex, 1, 64);
      const float w0 = odd ? ox : ex;
      const float w1 = odd ? ex : ox;
      sumw0 += w0; sumw1 += w1;
#pragma unroll
      for (int k = 0; k < 4; ++k) {
        z0[k].x += w0 * xr[k].x; z0[k].y += w0 * xr[k].y;
        z0[k].z += w0 * xr[k].z; z0[k].w += w0 * xr[k].w;
        z1[k].x += w1 * xr[k].x; z1[k].y += w1 * xr[k].y;
        z1[k].z += w1 * xr[k].z; z1[k].w += w1 * xr[k].w;
      }
    }
    __syncthreads();
  }
  float (*zs)[E_DIM] = (float(*)[E_DIM])&sbuf[0][0][0];
  {
    float4* zd0 = (float4*)&zs[2 * wave][0];
    float4* zd1 = (float4*)&zs[2 * wave + 1][0];
#pragma unroll
    for (int k = 0; k < 4; ++k) { zd0[64 * k + lane] = z0[k]; zd1[64 * k + lane] = z1[k]; }
  }
  if (lane == 0) { swst[2 * wave] = sumw0; swst[2 * wave + 1] = sumw1; }
  __syncthreads();
  {
    const float4* zsv = (const float4*)&zs[0][0];
    float4* pzb = (float4*)(partial_z + (size_t)blockIdx.x * (NHEAD * E_DIM));
#pragma unroll
    for (int j = 0; j < 4; ++j) {
      const int idx = t + 512 * j;
      const float4 a = zsv[idx], b = zsv[idx + 2048];
      pzb[idx] = make_float4(a.x + b.x, a.y + b.y, a.z + b.z, a.w + b.w);
    }
  }
  if (t < NHEAD)
    partial_sumw[blockIdx.x * NHEAD + t] = swst[t] + swst[t + 8];
}

// ---- reduce partials: zn[h][e] = sum_b pz / sum_b psumw (v6 verbatim) ----
__global__ __launch_bounds__(256) void reduce_z(
    const float* __restrict__ partial_z, const float* __restrict__ partial_sumw,
    float* __restrict__ zn, int nblk)
{
  __shared__ float red[256];
  __shared__ __align__(16) float swst[4][NHEAD];
  __shared__ float sumw_s[NHEAD];
  const int t = threadIdx.x;
  const int lane = t & 63, wave = t >> 6;
  float sw[NHEAD];
#pragma unroll
  for (int h = 0; h < NHEAD; ++h) sw[h] = 0.f;
  for (int b = t; b < nblk; b += 256) {
    const float4* p = (const float4*)(partial_sumw + (size_t)b * NHEAD);
    float4 a0 = p[0], a1 = p[1];
    sw[0] += a0.x; sw[1] += a0.y; sw[2] += a0.z; sw[3] += a0.w;
    sw[4] += a1.x; sw[5] += a1.y; sw[6] += a1.z; sw[7] += a1.w;
  }
#pragma unroll
  for (int m = 1; m < 64; m <<= 1) {
#pragma unroll
    for (int h = 0; h < NHEAD; ++h) sw[h] += __shfl_xor(sw[h], m, 64);
  }
  if (lane == 0) {
#pragma unroll
    for (int h = 0; h < NHEAD; ++h) swst[wave][h] = sw[h];
  }
  __syncthreads();
  if (t < NHEAD) sumw_s[t] = swst[0][t] + swst[1][t] + swst[2][t] + swst[3][t];
  const int o = blockIdx.x * 32 + (t & 31);
  const int g = t >> 5;
  float a = 0.f;
  for (int b = g; b < nblk; b += 8) a += partial_z[(size_t)b * (NHEAD * E_DIM) + o];
  red[t] = a;
  __syncthreads();
  if (t < 32) {
    float s2 = 0.f;
#pragma unroll
    for (int gg = 0; gg < 8; ++gg) s2 += red[gg * 32 + t];
    const int oo = blockIdx.x * 32 + t;
    zn[oo] = s2 / sumw_s[oo >> 10];   // oo = h*1024 + e
  }
}

// ---- attn[o] = Wv[o] . zn[h(o)] + bv[o] (v6 verbatim) ----
__global__ __launch_bounds__(256) void proj_v(
    const float* __restrict__ W, const float* __restrict__ bias,
    const float* __restrict__ zn, float* __restrict__ attn)
{
  const int t = threadIdx.x, wave = t >> 6, lane = t & 63;
  const int o = blockIdx.x * 4 + wave;
  const float4* Wr = (const float4*)(W + ((size_t)2 * E_DIM + o) * E_DIM);
  const float4* zr = (const float4*)(zn + (size_t)(o >> 7) * E_DIM);
  float a = 0.f;
#pragma unroll
  for (int k = 0; k < 4; ++k) {
    float4 wv = Wr[lane + 64 * k];
    float4 zv = zr[lane + 64 * k];
    a += wv.x * zv.x + wv.y * zv.y + wv.z * zv.z + wv.w * zv.w;
  }
#pragma unroll
  for (int m = 1; m < 64; m <<= 1) a += __shfl_xor(a, m, 64);
  if (lane == 0) attn[o] = a + bias[2 * E_DIM + o];
}

// ---- out[e] = Wo[e] . attn + bo[e] (v6 verbatim) ----
__global__ __launch_bounds__(256) void proj_o(
    const float* __restrict__ Wo, const float* __restrict__ bo,
    const float* __restrict__ attn, float* __restrict__ out)
{
  const int t = threadIdx.x, wave = t >> 6, lane = t & 63;
  const int o = blockIdx.x * 4 + wave;
  const float4* Wr = (const float4*)(Wo + (size_t)o * E_DIM);
  const float4* vr = (const float4*)attn;
  float a = 0.f;
#pragma unroll
  for (int k = 0; k < 4; ++k) {
    float4 wv = Wr[lane + 64 * k];
    float4 vv = vr[lane + 64 * k];
    a += wv.x * vv.x + wv.y * vv.y + wv.z * vv.z + wv.w * vv.w;
  }
#pragma unroll
  for (int m = 1; m < 64; m <<= 1) a += __shfl_xor(a, m, 64);
  if (lane == 0) out[o] = a + bo[o];
}

extern "C" void kernel_launch(void* const* d_in, const int* in_sizes, int n_in,
                              void* d_out, int out_size, void* d_ws, size_t ws_size,
                              hipStream_t stream)
{
  const float* x  = (const float*)d_in[0];   // [32768,1024]
  const float* Wi = (const float*)d_in[1];   // [3072,1024]
  const float* bi = (const float*)d_in[2];   // [3072]
  const float* Wo = (const float*)d_in[3];   // [1024,1024]
  const float* bo = (const float*)d_in[4];   // [1024]
  float* out = (float*)d_out;                // [1024] fp32

  // workspace layout (bytes)
  char* ws = (char*)d_ws;
  float* q     = (float*)(ws + 0);          // 1024 f
  float* P_T   = (float*)(ws + 4096);       // 8192 f
  float* zn    = (float*)(ws + 36864);      // 8192 f
  float* attn  = (float*)(ws + 69632);      // 1024 f
  float* psumw = (float*)(ws + 73728);      // nblk*8 f (<= 16 KB)
  const size_t pz_off = 90112;
  float* pz    = (float*)(ws + pz_off);     // nblk*8192 f

  // pick partial-block count from available workspace (constant across calls)
  int nblk = 128;
  if (ws_size >= pz_off + (size_t)512 * NHEAD * E_DIM * 4) nblk = 512;
  else if (ws_size >= pz_off + (size_t)256 * NHEAD * E_DIM * 4) nblk = 256;
  const int rows_per_blk = L_SEQ / nblk;

  proj_q     <<<256, 256, 0, stream>>>(Wi, bi, x, q);
  make_p2    <<<dim3(32, 8), 256, 0, stream>>>(Wi, q, P_T);
  attn_fused5<<<nblk, 512, 0, stream>>>(x, P_T, pz, psumw, rows_per_blk);
  reduce_z   <<<256, 256, 0, stream>>>(pz, psumw, zn, nblk);
  proj_v     <<<256, 256, 0, stream>>>(Wi, bi, zn, attn);
  proj_o     <<<256, 256, 0, stream>>>(Wo, bo, attn, out);
}